// Round 14
// baseline (53.976 us; speedup 1.0000x reference)
//
#include <hip/hip_runtime.h>
#include <hip/hip_bf16.h>
#include <math.h>

#define NB 2
#define NT 256
#define NN 512
#define NH 64
#define NS 8
#define NC 8

// workspace layout (float offsets)
#define OFF_H      0          // 65536  h f32
#define OFF_PVEC   65536      // 65536  pre_i + be1
#define OFF_HF16   131072     // 32768 dwords: h packed f16
#define OFF_HNF16  163840     // 32768 dwords: h*invnorm packed f16
#define OFF_WA16   196608     // 2048 floats = 4096 f16 (Wa frags, 32x32 layout)
#define OFF_WJF    198656     // 4096 floats (Wj, frag order)
#define OFF_WPF    202752     // 4096 floats (Wp, frag order)
#define OFF_GEXT   206848     // 524288: be2 + spss*cos + spps*prior
#define OFF_UNSYM  731136     // 524288

typedef __attribute__((ext_vector_type(8)))  _Float16 h8;
typedef __attribute__((ext_vector_type(2)))  __fp16   fp16x2;
typedef __attribute__((ext_vector_type(4)))  float    f32x4;
typedef __attribute__((ext_vector_type(16))) float    f32x16;
typedef __attribute__((ext_vector_type(4)))  unsigned u4;

__device__ __forceinline__ float softplusf(float x){
  if (x > 20.f) return x;
  return log1pf(expf(x));
}

__device__ __forceinline__ unsigned pkh(float a, float b){
  fp16x2 h = __builtin_amdgcn_cvt_pkrtz(a, b);
  return __builtin_bit_cast(unsigned, h);
}

template<int CTRL>
__device__ __forceinline__ float dpp_addf(float x){
  int xi = __builtin_bit_cast(int, x);
  int yi = __builtin_amdgcn_update_dpp(0, xi, CTRL, 0xF, 0xF, true);
  return x + __builtin_bit_cast(float, yi);
}
__device__ __forceinline__ float row16_sum(float x){
  x = dpp_addf<0xB1>(x);    // lane^1
  x = dpp_addf<0x4E>(x);    // lane^2
  x = dpp_addf<0x141>(x);   // lane^7
  x = dpp_addf<0x140>(x);   // lane^15
  return x;
}

// ---------------- Kernel FRONT: stats + node MLP + weight prep ----------------
// prep frags now in 32x32x16 B layout: frag f = s*2+nh; lane: n = nh*32+(l&31),
// k = s*16 + (l>>5)*8 + e.
__global__ __launch_bounds__(256) void k_front(
    const float* __restrict__ x, const float* __restrict__ mask,
    const float* __restrict__ sctx,
    const float* __restrict__ W1, const float* __restrict__ b1,
    const float* __restrict__ W2, const float* __restrict__ b2,
    const float* __restrict__ We1, const float* __restrict__ be1,
    float* __restrict__ hg, float* __restrict__ pvec,
    unsigned* __restrict__ hf16, unsigned* __restrict__ hn16,
    short* __restrict__ wa16, float* __restrict__ wjf,
    float* __restrict__ wpf){
  int blk = blockIdx.x;
  int tid = threadIdx.x;

  if (blk >= 256){
    int pidx = (blk - 256)*256 + tid;        // 0..12287
    int e    = pidx & 7;
    int lane = (pidx >> 3) & 63;
    int frag = (pidx >> 9) & 7;              // s*2 + nh
    int nh = frag & 1, s = frag >> 1;
    int k  = s*16 + (lane >> 5)*8 + e;       // 0..63
    int n  = nh*32 + (lane & 31);
    if (pidx < 4096){
      _Float16 v = (_Float16)We1[(128 + k)*NH + n];        // Wa rows 128..191
      wa16[pidx] = __builtin_bit_cast(short, v);
    } else if (pidx < 8192){
      wjf[pidx - 4096] = We1[(64 + k)*NH + n];             // Wj rows 64..127
    } else {
      wpf[pidx - 8192] = We1[(192 + k)*NH + n];            // Wp rows 192..255
    }
    return;
  }

  int b  = blk >> 7;
  int n0 = (blk & 127) * 4;

  // ---- stats: 4 nl x 64 ts ----
  int nl = tid & 3;
  int ts = tid >> 2;
  int n  = n0 + nl;

  float cnt = 0.f, sx = 0.f, sxx = 0.f;
  int lastt = 0;
  for (int t = ts*4; t < ts*4 + 4; ++t){
    int idx = (b*NT + t)*NN + n;
    float xv = x[idx];
    float mv = mask[idx];
    bool obs = (mv < 0.5f);
    if (obs){ cnt += 1.f; sx += xv; sxx += xv*xv; lastt = t; }
  }
  #pragma unroll
  for (int m = 4; m < 64; m <<= 1){
    cnt   += __shfl_xor(cnt,  m);
    sx    += __shfl_xor(sx,   m);
    sxx   += __shfl_xor(sxx,  m);
    lastt  = max(lastt, __shfl_xor(lastt, m));
  }
  int w = tid >> 6;
  __shared__ float r_cnt[4][4], r_sx[4][4], r_sxx[4][4];
  __shared__ int   r_lt[4][4];
  __shared__ float s_dyn[4][4];
  if ((tid & 63) < 4){
    r_cnt[w][nl] = cnt; r_sx[w][nl] = sx; r_sxx[w][nl] = sxx; r_lt[w][nl] = lastt;
  }
  __syncthreads();
  if (tid < 4){
    float c = 0.f, s1 = 0.f, s2 = 0.f; int lt = 0;
    #pragma unroll
    for (int ww = 0; ww < 4; ++ww){
      c  += r_cnt[ww][tid]; s1 += r_sx[ww][tid]; s2 += r_sxx[ww][tid];
      lt  = max(lt, r_lt[ww][tid]);
    }
    float cc   = fmaxf(c, 1.f);
    float mean = s1 / cc;
    float var  = s2 / cc - mean*mean;
    float stdv = sqrtf(fmaxf(var, 0.f) + 1e-6f);
    float last = x[(b*NT + lt)*NN + n0 + tid];
    float mr   = 1.f - c * (1.f/(float)NT);
    s_dyn[tid][0] = mean; s_dyn[tid][1] = stdv; s_dyn[tid][2] = last; s_dyn[tid][3] = mr;
  }
  __syncthreads();

  // ---- node MLP: wave w = node n0+w, lane c = channel ----
  int c = tid & 63;
  int gn = n0 + w;
  int bn = b*NN + gn;
  __shared__ float s_f[4][12];
  __shared__ float s_h1[4][64];
  __shared__ float s_h2[4][64];

  if (c < 4)       s_f[w][c] = s_dyn[w][c];
  else if (c < 12) s_f[w][c] = sctx[gn*NS + (c-4)];
  __syncthreads();

  float a = b1[c];
  #pragma unroll
  for (int k = 0; k < 12; ++k) a = fmaf(s_f[w][k], W1[k*NH + c], a);
  s_h1[w][c] = fmaxf(a, 0.f);
  __syncthreads();

  float a2 = b2[c];
  #pragma unroll 8
  for (int k = 0; k < 64; ++k) a2 = fmaf(s_h1[w][k], W2[k*NH + c], a2);
  a2 = fmaxf(a2, 0.f);

  float sq = a2*a2;
  #pragma unroll
  for (int m = 1; m < 64; m <<= 1) sq += __shfl_xor(sq, m);
  float inv = 1.f / fmaxf(sqrtf(sq), 1e-12f);

  s_h2[w][c] = a2;
  __syncthreads();

  float pi = be1[c];
  #pragma unroll 8
  for (int k = 0; k < 64; ++k) pi = fmaf(s_h2[w][k], We1[k*NH + c], pi);  // Wi

  hg  [bn*64 + c] = a2;
  pvec[bn*64 + c] = pi;
  if (c < 32){
    float e0 = s_h2[w][2*c], e1 = s_h2[w][2*c + 1];
    hf16[bn*32 + c] = pkh(e0, e1);
    hn16[bn*32 + c] = pkh(e0*inv, e1*inv);
  }
}

// ---------------- Kernel EXTRA: gext = be2 + spss*cos + spps*prior ----------
__global__ __launch_bounds__(256) void k_extra(
    const unsigned* __restrict__ hn16, const float* __restrict__ coords,
    const float* __restrict__ s_ss, const float* __restrict__ s_ps,
    const float* __restrict__ be2, float* __restrict__ gext){
  int b   = blockIdx.x;
  int i0  = blockIdx.y * 16;
  int jq  = blockIdx.z;
  int tid = threadIdx.x;
  int w   = tid >> 6;
  int lane = tid & 63;
  float spss = softplusf(s_ss[0]);
  float spps = softplusf(s_ps[0]);
  float be2v = be2[0];

  const u4* hv = (const u4*)hn16;
  int arow = i0 + (lane & 15);
  u4 a0 = hv[(b*NN + arow)*8 + (lane >> 4)];
  u4 a1 = hv[(b*NN + arow)*8 + (lane >> 4) + 4];
  h8 A0 = __builtin_bit_cast(h8, a0);
  h8 A1 = __builtin_bit_cast(h8, a1);

  #pragma unroll
  for (int t = 0; t < 2; ++t){
    int j0 = (jq*8 + w*2 + t) * 16;
    int jrow = j0 + (lane & 15);
    u4 b0 = hv[(b*NN + jrow)*8 + (lane >> 4)];
    u4 b1 = hv[(b*NN + jrow)*8 + (lane >> 4) + 4];
    f32x4 acc = (f32x4){0.f, 0.f, 0.f, 0.f};
    acc = __builtin_amdgcn_mfma_f32_16x16x32_f16(A0, __builtin_bit_cast(h8, b0), acc, 0, 0, 0);
    acc = __builtin_amdgcn_mfma_f32_16x16x32_f16(A1, __builtin_bit_cast(h8, b1), acc, 0, 0, 0);

    int jc = j0 + (lane & 15);
    float4 cj0 = *(const float4*)(coords + jc*NC);
    float4 cj1 = *(const float4*)(coords + jc*NC + 4);
    #pragma unroll
    for (int r = 0; r < 4; ++r){
      int irow = i0 + (lane >> 4)*4 + r;
      float4 ci0 = *(const float4*)(coords + irow*NC);
      float4 ci1 = *(const float4*)(coords + irow*NC + 4);
      float dd = 0.f;
      dd = fmaf(ci0.x-cj0.x, ci0.x-cj0.x, dd);
      dd = fmaf(ci0.y-cj0.y, ci0.y-cj0.y, dd);
      dd = fmaf(ci0.z-cj0.z, ci0.z-cj0.z, dd);
      dd = fmaf(ci0.w-cj0.w, ci0.w-cj0.w, dd);
      dd = fmaf(ci1.x-cj1.x, ci1.x-cj1.x, dd);
      dd = fmaf(ci1.y-cj1.y, ci1.y-cj1.y, dd);
      dd = fmaf(ci1.z-cj1.z, ci1.z-cj1.z, dd);
      dd = fmaf(ci1.w-cj1.w, ci1.w-cj1.w, dd);
      float dist  = sqrtf(fmaxf(dd, 1e-12f));
      float prior = (irow == jc) ? 0.f : spps / (1.f + dist);
      gext[(size_t)(b*NN + irow)*NN + jc] = fmaf(spss, acc[r], be2v + prior);
    }
  }
}

// ---------------- Kernel LOGITS: 32x32 MFMA + block panel + fused softmax ----
// grid NB*NN/2 (2 i-rows/block), 512 thr = 8 waves. Wave w: j-tiles w and w+8
// (32 j each). hj panel staged block-wide in 2 phases of 256 rows.
__global__ __launch_bounds__(512, 2) void k_logits(
    const float* __restrict__ hg, const float* __restrict__ pvec,
    const unsigned* __restrict__ hf16, const short* __restrict__ wa16,
    const float* __restrict__ wjf, const float* __restrict__ wpf,
    const float* __restrict__ We2, const float* __restrict__ gext,
    const float* __restrict__ s_sl, const float* __restrict__ s_tp,
    float* __restrict__ unsym){
  int blk = blockIdx.x;
  int b  = blk >> 8;
  int ip = (blk & 255) * 2;
  int tid  = threadIdx.x;
  int w    = tid >> 6;
  int lane = tid & 63;
  int jl   = lane & 31;       // A-row (j-local) / B-col (channel)
  int kh   = lane >> 5;       // k-half selector

  __shared__ __align__(16) unsigned panel[256*34];     // 34,816 B (f16 rows, pad 34dw)
  __shared__ __align__(16) unsigned lds_wa[2048];      //  8,192 B
  __shared__ __align__(16) unsigned lds_cw[2][2048];   // 16,384 B
  __shared__ __align__(16) float lrow[2][NN];          //  4,096 B
  __shared__ __align__(16) float s_hi[2][64];          //    512 B
  float* red = (float*)panel;                          // alias (panel dead post-loop)

  float spsl = softplusf(s_sl[0]);
  float invt = 1.f / (softplusf(s_tp[0]) + 1e-4f);

  if (tid < 128)
    s_hi[tid >> 6][tid & 63] = hg[(b*NN + ip + (tid >> 6))*64 + (tid & 63)];

  // stage panel phase 0: j rows 0..255 (coalesced, 64B/thread)
  {
    int row = tid >> 1, half = tid & 1;
    const u4* src = (const u4*)(hf16 + (size_t)(b*NN + row)*32 + half*16);
    unsigned* dst = panel + row*34 + half*16;
    u4 v0 = src[0], v1 = src[1], v2 = src[2], v3 = src[3];
    *(u4*)(dst)      = v0;
    *(u4*)(dst + 4)  = v1;
    *(u4*)(dst + 8)  = v2;
    *(u4*)(dst + 12) = v3;
  }
  __syncthreads();     // s_hi + panel0 ready

  // B-frags: wa copy + per-row cw = f16(Wj + diag(hi)*Wp)
  {
    int frag = tid >> 6;            // s*2+nh
    int l2   = tid & 63;
    *(u4*)&lds_wa[(frag*64 + l2)*4] = ((const u4*)wa16)[frag*64 + l2];

    int cb = (frag >> 1)*16 + (l2 >> 5)*8;     // channel base
    const float* wj = wjf + (frag*64 + l2)*8;
    const float* wp = wpf + (frag*64 + l2)*8;
    #pragma unroll
    for (int r = 0; r < 2; ++r){
      u4 u;
      #pragma unroll
      for (int d = 0; d < 4; ++d){
        float v0 = fmaf(s_hi[r][cb + 2*d],     wp[2*d],     wj[2*d]);
        float v1 = fmaf(s_hi[r][cb + 2*d + 1], wp[2*d + 1], wj[2*d + 1]);
        u[d] = pkh(v0, v1);
      }
      *(u4*)&lds_cw[r][(frag*64 + l2)*4] = u;
    }
  }

  // hi fragments (per lane: channels s*16 + kh*8 .. +7, s=0..3) for both rows
  u4 hiF[2][4];
  #pragma unroll
  for (int r = 0; r < 2; ++r)
    #pragma unroll
    for (int s = 0; s < 4; ++s)
      hiF[r][s] = *(const u4*)(hf16 + (size_t)(b*NN + ip + r)*32 + s*8 + kh*4);

  float pvv[2][2], we2v[2];
  #pragma unroll
  for (int nh = 0; nh < 2; ++nh){
    #pragma unroll
    for (int r = 0; r < 2; ++r)
      pvv[r][nh] = pvec[(b*NN + ip + r)*64 + nh*32 + jl];
    we2v[nh] = We2[nh*32 + jl];
  }
  __syncthreads();     // lds_wa / lds_cw ready

  const u4 absm = (u4){0x7fff7fffu, 0x7fff7fffu, 0x7fff7fffu, 0x7fff7fffu};

  #pragma unroll
  for (int phase = 0; phase < 2; ++phase){
    if (phase == 1){
      __syncthreads();   // all waves done reading panel0
      int row = tid >> 1, half = tid & 1;
      const u4* src = (const u4*)(hf16 + (size_t)(b*NN + 256 + row)*32 + half*16);
      unsigned* dst = panel + row*34 + half*16;
      u4 v0 = src[0], v1 = src[1], v2 = src[2], v3 = src[3];
      *(u4*)(dst)      = v0;
      *(u4*)(dst + 4)  = v1;
      *(u4*)(dst + 8)  = v2;
      *(u4*)(dst + 12) = v3;
      __syncthreads();
    }
    int jbase = (w + phase*8) * 32;
    int lr    = w*32 + jl;          // local panel row

    // hj fragments from panel (2-way-free: stride 34dw)
    u4 hjF[4];
    const unsigned* prow = panel + lr*34 + kh*4;
    #pragma unroll
    for (int s = 0; s < 4; ++s) hjF[s] = *(const u4*)(prow + s*8);

    f32x16 acc[2][2];
    #pragma unroll
    for (int r = 0; r < 2; ++r)
      #pragma unroll
      for (int nh = 0; nh < 2; ++nh)
        #pragma unroll
        for (int e = 0; e < 16; ++e) acc[r][nh][e] = pvv[r][nh];

    #pragma unroll
    for (int s = 0; s < 4; ++s){
      h8 hjv = __builtin_bit_cast(h8, hjF[s]);
      h8 wA0 = __builtin_bit_cast(h8, *(const u4*)&lds_wa[((s*2 + 0)*64 + lane)*4]);
      h8 wA1 = __builtin_bit_cast(h8, *(const u4*)&lds_wa[((s*2 + 1)*64 + lane)*4]);
      #pragma unroll
      for (int r = 0; r < 2; ++r){
        h8 dh = __builtin_bit_cast(h8, hiF[r][s]) - hjv;
        h8 ad = __builtin_bit_cast(h8, __builtin_bit_cast(u4, dh) & absm);
        h8 wC0 = __builtin_bit_cast(h8, *(const u4*)&lds_cw[r][((s*2 + 0)*64 + lane)*4]);
        h8 wC1 = __builtin_bit_cast(h8, *(const u4*)&lds_cw[r][((s*2 + 1)*64 + lane)*4]);
        acc[r][0] = __builtin_amdgcn_mfma_f32_32x32x16_f16(ad,  wA0, acc[r][0], 0, 0, 0);
        acc[r][1] = __builtin_amdgcn_mfma_f32_32x32x16_f16(ad,  wA1, acc[r][1], 0, 0, 0);
        acc[r][0] = __builtin_amdgcn_mfma_f32_32x32x16_f16(hjv, wC0, acc[r][0], 0, 0, 0);
        acc[r][1] = __builtin_amdgcn_mfma_f32_32x32x16_f16(hjv, wC1, acc[r][1], 0, 0, 0);
      }
    }

    // epilogue: relu + We2 dot, reduce over 32 channel-lanes, select+store
    #pragma unroll
    for (int r = 0; r < 2; ++r){
      float t[16];
      #pragma unroll
      for (int reg = 0; reg < 16; ++reg){
        float t0 = fmaxf(acc[r][0][reg], 0.f) * we2v[0];
        t[reg] = fmaf(fmaxf(acc[r][1][reg], 0.f), we2v[1], t0);
      }
      #pragma unroll
      for (int reg = 0; reg < 16; ++reg){
        t[reg] = row16_sum(t[reg]);
        t[reg] += __shfl_xor(t[reg], 16);
      }
      // static-index select: lane (lane&15) owns reg = lane&15
      float sel = t[0];
      #pragma unroll
      for (int reg = 1; reg < 16; ++reg) sel = ((lane & 15) == reg) ? t[reg] : sel;
      if ((lane & 31) < 16){
        int rr = lane & 15;
        int j2 = jbase + (rr & 3) + 8*(rr >> 2) + 4*kh;
        lrow[r][j2] = sel;
      }
    }
  }
  __syncthreads();

  // fused dual-row softmax; gext + diag folded here
  float ga = gext[(size_t)(b*NN + ip)*NN + tid];
  float gb = gext[(size_t)(b*NN + ip + 1)*NN + tid];
  float va = (tid == ip)     ? spsl : lrow[0][tid] + ga;
  float vb = (tid == ip + 1) ? spsl : lrow[1][tid] + gb;

  float ma = va, mb = vb;
  #pragma unroll
  for (int msk = 1; msk < 64; msk <<= 1){
    ma = fmaxf(ma, __shfl_xor(ma, msk));
    mb = fmaxf(mb, __shfl_xor(mb, msk));
  }
  if (lane == 0){ red[w] = ma; red[8 + w] = mb; }
  __syncthreads();
  ma = red[0]; mb = red[8];
  #pragma unroll
  for (int ww = 1; ww < 8; ++ww){
    ma = fmaxf(ma, red[ww]);
    mb = fmaxf(mb, red[8 + ww]);
  }

  float ea = expf((va - ma) * invt);
  float eb = expf((vb - mb) * invt);
  float sa = ea, sb = eb;
  #pragma unroll
  for (int msk = 1; msk < 64; msk <<= 1){
    sa += __shfl_xor(sa, msk);
    sb += __shfl_xor(sb, msk);
  }
  if (lane == 0){ red[16 + w] = sa; red[24 + w] = sb; }
  __syncthreads();
  sa = red[16]; sb = red[24];
  #pragma unroll
  for (int ww = 1; ww < 8; ++ww){
    sa += red[16 + ww];
    sb += red[24 + ww];
  }

  unsym[(size_t)(b*NN + ip)*NN + tid]     = ea / sa;
  unsym[(size_t)(b*NN + ip + 1)*NN + tid] = eb / sb;
}

// ---------------- Kernel D: symmetrize + renormalize ----------------
__global__ __launch_bounds__(256) void k_sym(
    const float* __restrict__ u, float* __restrict__ out){
  int blk = blockIdx.x;
  int b = blk >> 9, i = blk & (NN-1);
  int tid = threadIdx.x;
  const float* urow = u + (size_t)(b*NN + i) * NN;
  float v0, v1, rs;
  {
    int j0 = tid, j1 = tid + 256;
    float a1 = urow[j0];
    float a2 = u[(size_t)(b*NN + j0) * NN + i];
    v0 = 0.5f*(a1 + a2);
    float a3 = urow[j1];
    float a4 = u[(size_t)(b*NN + j1) * NN + i];
    v1 = 0.5f*(a3 + a4);
    rs = v0 + v1;
  }
  int lane = tid & 63, w = tid >> 6;
  #pragma unroll
  for (int msk = 1; msk < 64; msk <<= 1) rs += __shfl_xor(rs, msk);
  __shared__ float red[4];
  if (lane == 0) red[w] = rs;
  __syncthreads();
  rs = red[0] + red[1] + red[2] + red[3];
  float inv = 1.f / fmaxf(rs, 1e-6f);
  float* orow = out + (size_t)(b*NN + i) * NN;
  orow[tid]       = v0 * inv;
  orow[tid + 256] = v1 * inv;
}

extern "C" void kernel_launch(void* const* d_in, const int* in_sizes, int n_in,
                              void* d_out, int out_size, void* d_ws, size_t ws_size,
                              hipStream_t stream){
  const float* x      = (const float*)d_in[0];
  const float* mask   = (const float*)d_in[1];
  const float* sctx   = (const float*)d_in[2];
  const float* coords = (const float*)d_in[3];
  const float* W1     = (const float*)d_in[4];
  const float* b1     = (const float*)d_in[5];
  const float* W2     = (const float*)d_in[6];
  const float* b2     = (const float*)d_in[7];
  const float* We1    = (const float*)d_in[8];
  const float* be1    = (const float*)d_in[9];
  const float* We2    = (const float*)d_in[10];
  const float* be2    = (const float*)d_in[11];
  const float* sl     = (const float*)d_in[12];
  const float* ps     = (const float*)d_in[13];
  const float* ss     = (const float*)d_in[14];
  const float* tp     = (const float*)d_in[15];

  float*    ws    = (float*)d_ws;
  float*    hgp   = ws + OFF_H;
  float*    pvecp = ws + OFF_PVEC;
  unsigned* hf16p = (unsigned*)(ws + OFF_HF16);
  unsigned* hn16p = (unsigned*)(ws + OFF_HNF16);
  short*    wa16p = (short*)(ws + OFF_WA16);
  float*    wjfp  = ws + OFF_WJF;
  float*    wpfp  = ws + OFF_WPF;
  float*    gext  = ws + OFF_GEXT;
  float*    unsym = ws + OFF_UNSYM;
  float*    out   = (float*)d_out;

  k_front <<<304, 256, 0, stream>>>(x, mask, sctx, W1, b1, W2, b2, We1, be1,
                                    hgp, pvecp, hf16p, hn16p, wa16p, wjfp, wpfp);
  k_extra <<<dim3(NB, 32, 4), 256, 0, stream>>>(hn16p, coords, ss, ps, be2, gext);
  k_logits<<<NB*NN/2, 512, 0, stream>>>(hgp, pvecp, hf16p, wa16p, wjfp, wpfp,
                                        We2, gext, sl, tp, unsym);
  k_sym   <<<NB*NN, 256, 0, stream>>>(unsym, out);
}

// Round 16
// 43.761 us; speedup vs baseline: 1.2334x; 1.2334x over previous
//
#include <hip/hip_runtime.h>
#include <hip/hip_bf16.h>
#include <math.h>

#define NB 2
#define NT 256
#define NN 512
#define NH 64
#define NS 8
#define NC 8

// workspace layout (float offsets)
#define OFF_H      0          // 65536  h f32
#define OFF_PVEC   65536      // 65536  pre_i + be1
#define OFF_HF16   131072     // 32768 dwords: h packed f16
#define OFF_HNF16  163840     // 32768 dwords: h*invnorm packed f16
#define OFF_WA16   196608     // 2048 floats = 4096 f16 (Wa frags)
#define OFF_WJF    198656     // 4096 floats (Wj, frag order)
#define OFF_WPF    202752     // 4096 floats (Wp, frag order)
#define OFF_GEXT   206848     // 524288: be2 + spss*cos + spps*prior
#define OFF_UNSYM  731136     // 524288

typedef __attribute__((ext_vector_type(8))) _Float16 h8;
typedef __attribute__((ext_vector_type(2))) __fp16 fp16x2;
typedef __attribute__((ext_vector_type(4))) float f32x4;
typedef __attribute__((ext_vector_type(4))) unsigned u4;
typedef __attribute__((ext_vector_type(2))) unsigned u2;

__device__ __forceinline__ float softplusf(float x){
  if (x > 20.f) return x;
  return log1pf(expf(x));
}

__device__ __forceinline__ unsigned pkh(float a, float b){
  fp16x2 h = __builtin_amdgcn_cvt_pkrtz(a, b);
  return __builtin_bit_cast(unsigned, h);
}

template<int CTRL>
__device__ __forceinline__ float dpp_addf(float x){
  int xi = __builtin_bit_cast(int, x);
  int yi = __builtin_amdgcn_update_dpp(0, xi, CTRL, 0xF, 0xF, true);
  return x + __builtin_bit_cast(float, yi);
}
__device__ __forceinline__ float row16_sum(float x){
  x = dpp_addf<0xB1>(x);    // lane^1
  x = dpp_addf<0x4E>(x);    // lane^2
  x = dpp_addf<0x141>(x);   // lane^7
  x = dpp_addf<0x140>(x);   // lane^15
  return x;
}

// ---------------- Kernel FRONT: stats + node MLP + weight prep ----------------
__global__ __launch_bounds__(256) void k_front(
    const float* __restrict__ x, const float* __restrict__ mask,
    const float* __restrict__ sctx,
    const float* __restrict__ W1, const float* __restrict__ b1,
    const float* __restrict__ W2, const float* __restrict__ b2,
    const float* __restrict__ We1, const float* __restrict__ be1,
    float* __restrict__ hg, float* __restrict__ pvec,
    unsigned* __restrict__ hf16, unsigned* __restrict__ hn16,
    short* __restrict__ wa16, float* __restrict__ wjf,
    float* __restrict__ wpf){
  int blk = blockIdx.x;
  int tid = threadIdx.x;

  if (blk >= 256){
    int pidx = (blk - 256)*256 + tid;        // 0..12287
    int e    = pidx & 7;
    int lane = (pidx >> 3) & 63;
    int frag = (pidx >> 9) & 7;              // ks*4+nt
    int nt = frag & 3, ks = frag >> 2;
    int kg = lane >> 4, q = lane & 15;
    int kk = ks*32 + kg*8 + e;
    int c  = nt*16 + q;
    if (pidx < 4096){
      _Float16 v = (_Float16)We1[(128 + kk)*NH + c];       // Wa rows 128..191
      wa16[pidx] = __builtin_bit_cast(short, v);
    } else if (pidx < 8192){
      wjf[pidx - 4096] = We1[(64 + kk)*NH + c];            // Wj rows 64..127
    } else {
      wpf[pidx - 8192] = We1[(192 + kk)*NH + c];           // Wp rows 192..255
    }
    return;
  }

  int b  = blk >> 7;
  int n0 = (blk & 127) * 4;

  // ---- stats: 4 nl x 64 ts ----
  int nl = tid & 3;
  int ts = tid >> 2;
  int n  = n0 + nl;

  float cnt = 0.f, sx = 0.f, sxx = 0.f;
  int lastt = 0;
  for (int t = ts*4; t < ts*4 + 4; ++t){
    int idx = (b*NT + t)*NN + n;
    float xv = x[idx];
    float mv = mask[idx];
    bool obs = (mv < 0.5f);
    if (obs){ cnt += 1.f; sx += xv; sxx += xv*xv; lastt = t; }
  }
  #pragma unroll
  for (int m = 4; m < 64; m <<= 1){
    cnt   += __shfl_xor(cnt,  m);
    sx    += __shfl_xor(sx,   m);
    sxx   += __shfl_xor(sxx,  m);
    lastt  = max(lastt, __shfl_xor(lastt, m));
  }
  int w = tid >> 6;
  __shared__ float r_cnt[4][4], r_sx[4][4], r_sxx[4][4];
  __shared__ int   r_lt[4][4];
  __shared__ float s_dyn[4][4];
  if ((tid & 63) < 4){
    r_cnt[w][nl] = cnt; r_sx[w][nl] = sx; r_sxx[w][nl] = sxx; r_lt[w][nl] = lastt;
  }
  __syncthreads();
  if (tid < 4){
    float c = 0.f, s1 = 0.f, s2 = 0.f; int lt = 0;
    #pragma unroll
    for (int ww = 0; ww < 4; ++ww){
      c  += r_cnt[ww][tid]; s1 += r_sx[ww][tid]; s2 += r_sxx[ww][tid];
      lt  = max(lt, r_lt[ww][tid]);
    }
    float cc   = fmaxf(c, 1.f);
    float mean = s1 / cc;
    float var  = s2 / cc - mean*mean;
    float stdv = sqrtf(fmaxf(var, 0.f) + 1e-6f);
    float last = x[(b*NT + lt)*NN + n0 + tid];
    float mr   = 1.f - c * (1.f/(float)NT);
    s_dyn[tid][0] = mean; s_dyn[tid][1] = stdv; s_dyn[tid][2] = last; s_dyn[tid][3] = mr;
  }
  __syncthreads();

  // ---- node MLP: wave w = node n0+w, lane c = channel ----
  int c = tid & 63;
  int gn = n0 + w;
  int bn = b*NN + gn;
  __shared__ float s_f[4][12];
  __shared__ float s_h1[4][64];
  __shared__ float s_h2[4][64];

  if (c < 4)       s_f[w][c] = s_dyn[w][c];
  else if (c < 12) s_f[w][c] = sctx[gn*NS + (c-4)];
  __syncthreads();

  float a = b1[c];
  #pragma unroll
  for (int k = 0; k < 12; ++k) a = fmaf(s_f[w][k], W1[k*NH + c], a);
  s_h1[w][c] = fmaxf(a, 0.f);
  __syncthreads();

  float a2 = b2[c];
  #pragma unroll 8
  for (int k = 0; k < 64; ++k) a2 = fmaf(s_h1[w][k], W2[k*NH + c], a2);
  a2 = fmaxf(a2, 0.f);

  float sq = a2*a2;
  #pragma unroll
  for (int m = 1; m < 64; m <<= 1) sq += __shfl_xor(sq, m);
  float inv = 1.f / fmaxf(sqrtf(sq), 1e-12f);

  s_h2[w][c] = a2;
  __syncthreads();

  float pi = be1[c];
  #pragma unroll 8
  for (int k = 0; k < 64; ++k) pi = fmaf(s_h2[w][k], We1[k*NH + c], pi);  // Wi

  hg  [bn*64 + c] = a2;
  pvec[bn*64 + c] = pi;
  if (c < 32){
    float e0 = s_h2[w][2*c], e1 = s_h2[w][2*c + 1];
    hf16[bn*32 + c] = pkh(e0, e1);
    hn16[bn*32 + c] = pkh(e0*inv, e1*inv);
  }
}

// ---------------- Kernel EXTRA: gext = be2 + spss*cos + spps*prior ----------
__global__ __launch_bounds__(256) void k_extra(
    const unsigned* __restrict__ hn16, const float* __restrict__ coords,
    const float* __restrict__ s_ss, const float* __restrict__ s_ps,
    const float* __restrict__ be2, float* __restrict__ gext){
  int b   = blockIdx.x;
  int i0  = blockIdx.y * 16;
  int jq  = blockIdx.z;
  int tid = threadIdx.x;
  int w   = tid >> 6;
  int lane = tid & 63;
  float spss = softplusf(s_ss[0]);
  float spps = softplusf(s_ps[0]);
  float be2v = be2[0];

  const u4* hv = (const u4*)hn16;
  int arow = i0 + (lane & 15);
  u4 a0 = hv[(b*NN + arow)*8 + (lane >> 4)];
  u4 a1 = hv[(b*NN + arow)*8 + (lane >> 4) + 4];
  h8 A0 = __builtin_bit_cast(h8, a0);
  h8 A1 = __builtin_bit_cast(h8, a1);

  #pragma unroll
  for (int t = 0; t < 2; ++t){
    int j0 = (jq*8 + w*2 + t) * 16;
    int jrow = j0 + (lane & 15);
    u4 b0 = hv[(b*NN + jrow)*8 + (lane >> 4)];
    u4 b1 = hv[(b*NN + jrow)*8 + (lane >> 4) + 4];
    f32x4 acc = (f32x4){0.f, 0.f, 0.f, 0.f};
    acc = __builtin_amdgcn_mfma_f32_16x16x32_f16(A0, __builtin_bit_cast(h8, b0), acc, 0, 0, 0);
    acc = __builtin_amdgcn_mfma_f32_16x16x32_f16(A1, __builtin_bit_cast(h8, b1), acc, 0, 0, 0);

    int jc = j0 + (lane & 15);
    float4 cj0 = *(const float4*)(coords + jc*NC);
    float4 cj1 = *(const float4*)(coords + jc*NC + 4);
    #pragma unroll
    for (int r = 0; r < 4; ++r){
      int irow = i0 + (lane >> 4)*4 + r;
      float4 ci0 = *(const float4*)(coords + irow*NC);
      float4 ci1 = *(const float4*)(coords + irow*NC + 4);
      float dd = 0.f;
      dd = fmaf(ci0.x-cj0.x, ci0.x-cj0.x, dd);
      dd = fmaf(ci0.y-cj0.y, ci0.y-cj0.y, dd);
      dd = fmaf(ci0.z-cj0.z, ci0.z-cj0.z, dd);
      dd = fmaf(ci0.w-cj0.w, ci0.w-cj0.w, dd);
      dd = fmaf(ci1.x-cj1.x, ci1.x-cj1.x, dd);
      dd = fmaf(ci1.y-cj1.y, ci1.y-cj1.y, dd);
      dd = fmaf(ci1.z-cj1.z, ci1.z-cj1.z, dd);
      dd = fmaf(ci1.w-cj1.w, ci1.w-cj1.w, dd);
      float dist  = sqrtf(fmaxf(dd, 1e-12f));
      float prior = (irow == jc) ? 0.f : spps / (1.f + dist);
      gext[(size_t)(b*NN + irow)*NN + jc] = fmaf(spss, acc[r], be2v + prior);
    }
  }
}

// ---------------- Kernel LOGITS: 2 i-rows per block + fused softmax ----------
// grid NB*NN/2, 512 thr = 8 waves; wave: 4 j-tiles. features f16 [|hi-hj|;hj],
// B = [Wa ; Wj + diag(hi)Wp] in LDS. gext + diag applied at softmax time.
__global__ __launch_bounds__(512, 4) void k_logits(
    const float* __restrict__ hg, const float* __restrict__ pvec,
    const unsigned* __restrict__ hf16, const short* __restrict__ wa16,
    const float* __restrict__ wjf, const float* __restrict__ wpf,
    const float* __restrict__ We2, const float* __restrict__ gext,
    const float* __restrict__ s_sl, const float* __restrict__ s_tp,
    float* __restrict__ unsym){
  int blk = blockIdx.x;
  int b  = blk >> 8;
  int ip = (blk & 255) * 2;          // rows ip, ip+1
  int tid  = threadIdx.x;
  int w    = tid >> 6;
  int lane = tid & 63;
  int q    = lane & 15;
  int kg   = lane >> 4;

  __shared__ __align__(16) float s_hi[2][64];
  __shared__ __align__(16) float lrow[2][NN];
  __shared__ __align__(16) unsigned lds_wa[2048];     // 8 frags x 64 x 4dw
  __shared__ __align__(16) unsigned lds_cw[2][2048];
  __shared__ __align__(16) unsigned s_hj[8][16*34 + 2];
  __shared__ float red[32];

  float spsl = softplusf(s_sl[0]);
  float invt = 1.f / (softplusf(s_tp[0]) + 1e-4f);

  if (tid < 128)
    s_hi[tid >> 6][tid & 63] = hg[(b*NN + ip + (tid >> 6))*64 + (tid & 63)];
  __syncthreads();   // s_hi ready

  // B-frags in LDS: wa copy + per-row cw = f16(Wj + diag(hi)*Wp)
  {
    int frag = tid >> 6;          // 0..7 = ks*4+nt
    int l2   = tid & 63;
    const u4* wsrc = (const u4*)wa16;
    *(u4*)&lds_wa[(frag*64 + l2)*4] = wsrc[frag*64 + l2];

    int ch0 = (frag >> 2)*32 + (l2 >> 4)*8;
    const float* wj = wjf + (frag*64 + l2)*8;
    const float* wp = wpf + (frag*64 + l2)*8;
    #pragma unroll
    for (int r = 0; r < 2; ++r){
      u4 u;
      #pragma unroll
      for (int d = 0; d < 4; ++d){
        float v0 = fmaf(s_hi[r][ch0 + 2*d],     wp[2*d],     wj[2*d]);
        float v1 = fmaf(s_hi[r][ch0 + 2*d + 1], wp[2*d + 1], wj[2*d + 1]);
        u[d] = pkh(v0, v1);
      }
      *(u4*)&lds_cw[r][(frag*64 + l2)*4] = u;
    }
  }

  // per-lane hi packed f16 for both rows
  const u4* hfv = (const u4*)hf16;
  u4 hiA[2][2];
  #pragma unroll
  for (int r = 0; r < 2; ++r){
    hiA[r][0] = hfv[(b*NN + ip + r)*8 + kg];
    hiA[r][1] = hfv[(b*NN + ip + r)*8 + kg + 4];
  }

  float pv4[2][4], we2q[4];
  #pragma unroll
  for (int nt = 0; nt < 4; ++nt){
    #pragma unroll
    for (int r = 0; r < 2; ++r)
      pv4[r][nt] = pvec[(b*NN + ip + r)*64 + nt*16 + q];
    we2q[nt] = We2[nt*16 + q];
  }
  __syncthreads();   // lds_wa / lds_cw ready

  unsigned* slice = &s_hj[w][0];
  const u4 absm = (u4){0x7fff7fffu, 0x7fff7fffu, 0x7fff7fffu, 0x7fff7fffu};

  #pragma unroll
  for (int s = 0; s < 4; ++s){
    int it = w + s*8;
    int jbase = it * 16;

    // stage hj tile (16 rows x 64 ch f16 = 2 KB) coalesced -> wave-private LDS
    {
      int r8 = lane >> 3, c8 = lane & 7;
      u4 g0 = *(const u4*)((const unsigned*)hf16 + (size_t)(b*NN + jbase + r8)*32 + c8*4);
      u4 g1 = *(const u4*)((const unsigned*)hf16 + (size_t)(b*NN + jbase + 8 + r8)*32 + c8*4);
      unsigned* p0 = slice + r8*34 + c8*4;
      unsigned* p1 = slice + (8 + r8)*34 + c8*4;
      u2 t;
      t.x = g0.x; t.y = g0.y; *(u2*)p0 = t;
      t.x = g0.z; t.y = g0.w; *(u2*)(p0 + 2) = t;
      t.x = g1.x; t.y = g1.y; *(u2*)p1 = t;
      t.x = g1.z; t.y = g1.w; *(u2*)(p1 + 2) = t;
    }

    // this lane's hj fragment (row q, k-slices kg)
    u4 hj0, hj1;
    {
      unsigned* rp = slice + q*34 + kg*4;
      u2 a0 = *(u2*)rp;
      u2 a1 = *(u2*)(rp + 2);
      u2 b0 = *(u2*)(rp + 16);
      u2 b1 = *(u2*)(rp + 18);
      hj0.x = a0.x; hj0.y = a0.y; hj0.z = a1.x; hj0.w = a1.y;
      hj1.x = b0.x; hj1.y = b0.y; hj1.z = b1.x; hj1.w = b1.y;
    }
    h8 hjv0 = __builtin_bit_cast(h8, hj0);
    h8 hjv1 = __builtin_bit_cast(h8, hj1);

    f32x4 acc[2][4];
    #pragma unroll
    for (int r = 0; r < 2; ++r)
      #pragma unroll
      for (int nt = 0; nt < 4; ++nt)
        acc[r][nt] = (f32x4){pv4[r][nt], pv4[r][nt], pv4[r][nt], pv4[r][nt]};

    #pragma unroll
    for (int nt = 0; nt < 4; ++nt){
      h8 wA0 = __builtin_bit_cast(h8, *(const u4*)&lds_wa[((0*4 + nt)*64 + lane)*4]);
      h8 wA1 = __builtin_bit_cast(h8, *(const u4*)&lds_wa[((1*4 + nt)*64 + lane)*4]);
      #pragma unroll
      for (int r = 0; r < 2; ++r){
        h8 dh0 = __builtin_bit_cast(h8, hiA[r][0]) - hjv0;
        h8 dh1 = __builtin_bit_cast(h8, hiA[r][1]) - hjv1;
        h8 af0 = __builtin_bit_cast(h8, __builtin_bit_cast(u4, dh0) & absm);
        h8 af1 = __builtin_bit_cast(h8, __builtin_bit_cast(u4, dh1) & absm);
        h8 wC0 = __builtin_bit_cast(h8, *(const u4*)&lds_cw[r][((0*4 + nt)*64 + lane)*4]);
        h8 wC1 = __builtin_bit_cast(h8, *(const u4*)&lds_cw[r][((1*4 + nt)*64 + lane)*4]);
        acc[r][nt] = __builtin_amdgcn_mfma_f32_16x16x32_f16(af0, wA0, acc[r][nt], 0, 0, 0);
        acc[r][nt] = __builtin_amdgcn_mfma_f32_16x16x32_f16(af1, wA1, acc[r][nt], 0, 0, 0);
        acc[r][nt] = __builtin_amdgcn_mfma_f32_16x16x32_f16(hjv0, wC0, acc[r][nt], 0, 0, 0);
        acc[r][nt] = __builtin_amdgcn_mfma_f32_16x16x32_f16(hjv1, wC1, acc[r][nt], 0, 0, 0);
      }
    }

    // epilogue per row: relu + We2 dot, DPP 16-lane reduce; raw MLP part only
    #pragma unroll
    for (int r = 0; r < 2; ++r){
      float part[4] = {0.f, 0.f, 0.f, 0.f};
      #pragma unroll
      for (int nt = 0; nt < 4; ++nt)
        #pragma unroll
        for (int rr = 0; rr < 4; ++rr)
          part[rr] = fmaf(fmaxf(acc[r][nt][rr], 0.f), we2q[nt], part[rr]);
      #pragma unroll
      for (int rr = 0; rr < 4; ++rr) part[rr] = row16_sum(part[rr]);

      if (q < 4){
        int j2 = jbase + kg*4 + q;
        float ps2 = part[0];
        ps2 = (q == 1) ? part[1] : ps2;
        ps2 = (q == 2) ? part[2] : ps2;
        ps2 = (q == 3) ? part[3] : ps2;
        lrow[r][j2] = ps2;
      }
    }
  }
  __syncthreads();

  // fused dual-row softmax; gext + diag applied here (one coalesced read/row)
  float ga = gext[(size_t)(b*NN + ip)*NN + tid];
  float gb = gext[(size_t)(b*NN + ip + 1)*NN + tid];
  float va = (tid == ip)     ? spsl : lrow[0][tid] + ga;
  float vb = (tid == ip + 1) ? spsl : lrow[1][tid] + gb;

  float ma = va, mb = vb;
  #pragma unroll
  for (int msk = 1; msk < 64; msk <<= 1){
    ma = fmaxf(ma, __shfl_xor(ma, msk));
    mb = fmaxf(mb, __shfl_xor(mb, msk));
  }
  if (lane == 0){ red[w] = ma; red[8 + w] = mb; }
  __syncthreads();
  ma = red[0]; mb = red[8];
  #pragma unroll
  for (int ww = 1; ww < 8; ++ww){
    ma = fmaxf(ma, red[ww]);
    mb = fmaxf(mb, red[8 + ww]);
  }

  float ea = expf((va - ma) * invt);
  float eb = expf((vb - mb) * invt);
  float sa = ea, sb = eb;
  #pragma unroll
  for (int msk = 1; msk < 64; msk <<= 1){
    sa += __shfl_xor(sa, msk);
    sb += __shfl_xor(sb, msk);
  }
  if (lane == 0){ red[16 + w] = sa; red[24 + w] = sb; }
  __syncthreads();
  sa = red[16]; sb = red[24];
  #pragma unroll
  for (int ww = 1; ww < 8; ++ww){
    sa += red[16 + ww];
    sb += red[24 + ww];
  }

  unsym[(size_t)(b*NN + ip)*NN + tid]       = ea / sa;
  unsym[(size_t)(b*NN + ip + 1)*NN + tid]   = eb / sb;
}

// ---------------- Kernel D: symmetrize + renormalize ----------------
__global__ __launch_bounds__(256) void k_sym(
    const float* __restrict__ u, float* __restrict__ out){
  int blk = blockIdx.x;
  int b = blk >> 9, i = blk & (NN-1);
  int tid = threadIdx.x;
  const float* urow = u + (size_t)(b*NN + i) * NN;
  float v0, v1, rs;
  {
    int j0 = tid, j1 = tid + 256;
    float a1 = urow[j0];
    float a2 = u[(size_t)(b*NN + j0) * NN + i];
    v0 = 0.5f*(a1 + a2);
    float a3 = urow[j1];
    float a4 = u[(size_t)(b*NN + j1) * NN + i];
    v1 = 0.5f*(a3 + a4);
    rs = v0 + v1;
  }
  int lane = tid & 63, w = tid >> 6;
  #pragma unroll
  for (int msk = 1; msk < 64; msk <<= 1) rs += __shfl_xor(rs, msk);
  __shared__ float red[4];
  if (lane == 0) red[w] = rs;
  __syncthreads();
  rs = red[0] + red[1] + red[2] + red[3];
  float inv = 1.f / fmaxf(rs, 1e-6f);
  float* orow = out + (size_t)(b*NN + i) * NN;
  orow[tid]       = v0 * inv;
  orow[tid + 256] = v1 * inv;
}

extern "C" void kernel_launch(void* const* d_in, const int* in_sizes, int n_in,
                              void* d_out, int out_size, void* d_ws, size_t ws_size,
                              hipStream_t stream){
  const float* x      = (const float*)d_in[0];
  const float* mask   = (const float*)d_in[1];
  const float* sctx   = (const float*)d_in[2];
  const float* coords = (const float*)d_in[3];
  const float* W1     = (const float*)d_in[4];
  const float* b1     = (const float*)d_in[5];
  const float* W2     = (const float*)d_in[6];
  const float* b2     = (const float*)d_in[7];
  const float* We1    = (const float*)d_in[8];
  const float* be1    = (const float*)d_in[9];
  const float* We2    = (const float*)d_in[10];
  const float* be2    = (const float*)d_in[11];
  const float* sl     = (const float*)d_in[12];
  const float* ps     = (const float*)d_in[13];
  const float* ss     = (const float*)d_in[14];
  const float* tp     = (const float*)d_in[15];

  float*    ws    = (float*)d_ws;
  float*    hgp   = ws + OFF_H;
  float*    pvecp = ws + OFF_PVEC;
  unsigned* hf16p = (unsigned*)(ws + OFF_HF16);
  unsigned* hn16p = (unsigned*)(ws + OFF_HNF16);
  short*    wa16p = (short*)(ws + OFF_WA16);
  float*    wjfp  = ws + OFF_WJF;
  float*    wpfp  = ws + OFF_WPF;
  float*    gext  = ws + OFF_GEXT;
  float*    unsym = ws + OFF_UNSYM;
  float*    out   = (float*)d_out;

  k_front <<<304, 256, 0, stream>>>(x, mask, sctx, W1, b1, W2, b2, We1, be1,
                                    hgp, pvecp, hf16p, hn16p, wa16p, wjfp, wpfp);
  k_extra <<<dim3(NB, 32, 4), 256, 0, stream>>>(hn16p, coords, ss, ps, be2, gext);
  k_logits<<<NB*NN/2, 512, 0, stream>>>(hgp, pvecp, hf16p, wa16p, wjfp, wpfp,
                                        We2, gext, sl, tp, unsym);
  k_sym   <<<NB*NN, 256, 0, stream>>>(unsym, out);
}

// Round 17
// 43.473 us; speedup vs baseline: 1.2416x; 1.0066x over previous
//
#include <hip/hip_runtime.h>
#include <hip/hip_bf16.h>
#include <math.h>

#define NB 2
#define NT 256
#define NN 512
#define NH 64
#define NS 8
#define NC 8

// workspace layout (float offsets)
#define OFF_H      0          // 65536  h f32
#define OFF_PVEC   65536      // 65536  pre_i + be1
#define OFF_HF16   131072     // 32768 dwords: h packed f16
#define OFF_INVN   163840     // 1024
#define OFF_WA16   164864     // 2048 floats = 4096 f16 (Wa frags)
#define OFF_WJF    166912     // 4096 floats (Wj, frag order)
#define OFF_WPF    171008     // 4096 floats (Wp, frag order)
#define OFF_UNSYM  175104     // 524288

typedef __attribute__((ext_vector_type(8))) _Float16 h8;
typedef __attribute__((ext_vector_type(2))) __fp16 fp16x2;
typedef __attribute__((ext_vector_type(4))) float f32x4;
typedef __attribute__((ext_vector_type(4))) unsigned u4;
typedef __attribute__((ext_vector_type(2))) unsigned u2;

__device__ __forceinline__ float softplusf(float x){
  if (x > 20.f) return x;
  return log1pf(expf(x));
}

__device__ __forceinline__ unsigned pkh(float a, float b){
  fp16x2 h = __builtin_amdgcn_cvt_pkrtz(a, b);
  return __builtin_bit_cast(unsigned, h);
}

// f32 += dot of packed f16 pairs
__device__ __forceinline__ float fdot2u(unsigned a, unsigned b, float c){
#if __has_builtin(__builtin_amdgcn_fdot2)
  return __builtin_amdgcn_fdot2(__builtin_bit_cast(fp16x2, a),
                                __builtin_bit_cast(fp16x2, b), c, false);
#else
  fp16x2 av = __builtin_bit_cast(fp16x2, a);
  fp16x2 bv = __builtin_bit_cast(fp16x2, b);
  return fmaf((float)av.x, (float)bv.x, fmaf((float)av.y, (float)bv.y, c));
#endif
}
__device__ __forceinline__ float dot8(u4 a, u4 b, float acc){
  #pragma unroll
  for (int d = 0; d < 4; ++d) acc = fdot2u(a[d], b[d], acc);
  return acc;
}

template<int CTRL>
__device__ __forceinline__ float dpp_addf(float x){
  int xi = __builtin_bit_cast(int, x);
  int yi = __builtin_amdgcn_update_dpp(0, xi, CTRL, 0xF, 0xF, true);
  return x + __builtin_bit_cast(float, yi);
}
__device__ __forceinline__ float row16_sum(float x){
  x = dpp_addf<0xB1>(x);    // lane^1
  x = dpp_addf<0x4E>(x);    // lane^2
  x = dpp_addf<0x141>(x);   // lane^7
  x = dpp_addf<0x140>(x);   // lane^15
  return x;
}

// ---------------- Kernel FRONT: stats + node MLP + weight prep ----------------
__global__ __launch_bounds__(256) void k_front(
    const float* __restrict__ x, const float* __restrict__ mask,
    const float* __restrict__ sctx,
    const float* __restrict__ W1, const float* __restrict__ b1,
    const float* __restrict__ W2, const float* __restrict__ b2,
    const float* __restrict__ We1, const float* __restrict__ be1,
    float* __restrict__ hg, float* __restrict__ pvec,
    unsigned* __restrict__ hf16, float* __restrict__ invn,
    short* __restrict__ wa16, float* __restrict__ wjf,
    float* __restrict__ wpf){
  int blk = blockIdx.x;
  int tid = threadIdx.x;

  if (blk >= 256){
    int pidx = (blk - 256)*256 + tid;        // 0..12287
    int e    = pidx & 7;
    int lane = (pidx >> 3) & 63;
    int frag = (pidx >> 9) & 7;              // ks*4+nt
    int nt = frag & 3, ks = frag >> 2;
    int kg = lane >> 4, q = lane & 15;
    int kk = ks*32 + kg*8 + e;
    int c  = nt*16 + q;
    if (pidx < 4096){
      _Float16 v = (_Float16)We1[(128 + kk)*NH + c];       // Wa rows 128..191
      wa16[pidx] = __builtin_bit_cast(short, v);
    } else if (pidx < 8192){
      wjf[pidx - 4096] = We1[(64 + kk)*NH + c];            // Wj rows 64..127
    } else {
      wpf[pidx - 8192] = We1[(192 + kk)*NH + c];           // Wp rows 192..255
    }
    return;
  }

  int b  = blk >> 7;
  int n0 = (blk & 127) * 4;

  // ---- stats: 4 nl x 64 ts ----
  int nl = tid & 3;
  int ts = tid >> 2;
  int n  = n0 + nl;

  float cnt = 0.f, sx = 0.f, sxx = 0.f;
  int lastt = 0;
  for (int t = ts*4; t < ts*4 + 4; ++t){
    int idx = (b*NT + t)*NN + n;
    float xv = x[idx];
    float mv = mask[idx];
    bool obs = (mv < 0.5f);
    if (obs){ cnt += 1.f; sx += xv; sxx += xv*xv; lastt = t; }
  }
  #pragma unroll
  for (int m = 4; m < 64; m <<= 1){
    cnt   += __shfl_xor(cnt,  m);
    sx    += __shfl_xor(sx,   m);
    sxx   += __shfl_xor(sxx,  m);
    lastt  = max(lastt, __shfl_xor(lastt, m));
  }
  int w = tid >> 6;
  __shared__ float r_cnt[4][4], r_sx[4][4], r_sxx[4][4];
  __shared__ int   r_lt[4][4];
  __shared__ float s_dyn[4][4];
  if ((tid & 63) < 4){
    r_cnt[w][nl] = cnt; r_sx[w][nl] = sx; r_sxx[w][nl] = sxx; r_lt[w][nl] = lastt;
  }
  __syncthreads();
  if (tid < 4){
    float c = 0.f, s1 = 0.f, s2 = 0.f; int lt = 0;
    #pragma unroll
    for (int ww = 0; ww < 4; ++ww){
      c  += r_cnt[ww][tid]; s1 += r_sx[ww][tid]; s2 += r_sxx[ww][tid];
      lt  = max(lt, r_lt[ww][tid]);
    }
    float cc   = fmaxf(c, 1.f);
    float mean = s1 / cc;
    float var  = s2 / cc - mean*mean;
    float stdv = sqrtf(fmaxf(var, 0.f) + 1e-6f);
    float last = x[(b*NT + lt)*NN + n0 + tid];
    float mr   = 1.f - c * (1.f/(float)NT);
    s_dyn[tid][0] = mean; s_dyn[tid][1] = stdv; s_dyn[tid][2] = last; s_dyn[tid][3] = mr;
  }
  __syncthreads();

  // ---- node MLP: wave w = node n0+w, lane c = channel ----
  int c = tid & 63;
  int gn = n0 + w;
  int bn = b*NN + gn;
  __shared__ float s_f[4][12];
  __shared__ float s_h1[4][64];
  __shared__ float s_h2[4][64];

  if (c < 4)       s_f[w][c] = s_dyn[w][c];
  else if (c < 12) s_f[w][c] = sctx[gn*NS + (c-4)];
  __syncthreads();

  float a = b1[c];
  #pragma unroll
  for (int k = 0; k < 12; ++k) a = fmaf(s_f[w][k], W1[k*NH + c], a);
  s_h1[w][c] = fmaxf(a, 0.f);
  __syncthreads();

  float a2 = b2[c];
  #pragma unroll 8
  for (int k = 0; k < 64; ++k) a2 = fmaf(s_h1[w][k], W2[k*NH + c], a2);
  a2 = fmaxf(a2, 0.f);

  float sq = a2*a2;
  #pragma unroll
  for (int m = 1; m < 64; m <<= 1) sq += __shfl_xor(sq, m);
  float inv = 1.f / fmaxf(sqrtf(sq), 1e-12f);

  s_h2[w][c] = a2;
  __syncthreads();

  float pi = be1[c];
  #pragma unroll 8
  for (int k = 0; k < 64; ++k) pi = fmaf(s_h2[w][k], We1[k*NH + c], pi);  // Wi

  hg  [bn*64 + c] = a2;
  pvec[bn*64 + c] = pi;
  if (c < 32){
    float e0 = s_h2[w][2*c], e1 = s_h2[w][2*c + 1];
    hf16[bn*32 + c] = pkh(e0, e1);
  }
  if (c == 0) invn[bn] = inv;
}

// ---------------- Kernel LOGITS: 2 i-rows/block, inline cos+prior, softmax ----
// grid NB*NN/2, 512 thr = 8 waves; wave: 4 j-tiles. features f16 [|hi-hj|;hj],
// B = [Wa ; Wj + diag(hi)Wp] in LDS. cos via fdot2, prior in setup.
__global__ __launch_bounds__(512, 4) void k_logits(
    const float* __restrict__ hg, const float* __restrict__ pvec,
    const unsigned* __restrict__ hf16, const float* __restrict__ invn,
    const short* __restrict__ wa16, const float* __restrict__ wjf,
    const float* __restrict__ wpf, const float* __restrict__ coords,
    const float* __restrict__ We2, const float* __restrict__ be2,
    const float* __restrict__ s_sl, const float* __restrict__ s_ps,
    const float* __restrict__ s_ss, const float* __restrict__ s_tp,
    float* __restrict__ unsym){
  int blk = blockIdx.x;
  int b  = blk >> 8;
  int ip = (blk & 255) * 2;          // rows ip, ip+1
  int tid  = threadIdx.x;
  int w    = tid >> 6;
  int lane = tid & 63;
  int q    = lane & 15;
  int kg   = lane >> 4;

  __shared__ __align__(16) float s_hi[2][64];
  __shared__ __align__(16) float s_pri[2][NN];     // be2 + spps*prior
  __shared__ __align__(16) float s_invn[NN];
  __shared__ __align__(16) float lrow[2][NN];
  __shared__ __align__(16) unsigned lds_wa[2048];  // 8 frags x 64 x 4dw
  __shared__ __align__(16) unsigned lds_cw[2][2048];
  __shared__ __align__(16) unsigned s_hj[8][16*34 + 2];
  __shared__ float red[32];

  float spsl = softplusf(s_sl[0]);
  float spps = softplusf(s_ps[0]);
  float spss = softplusf(s_ss[0]);
  float invt = 1.f / (softplusf(s_tp[0]) + 1e-4f);
  float be2v = be2[0];

  if (tid < 128)
    s_hi[tid >> 6][tid & 63] = hg[(b*NN + ip + (tid >> 6))*64 + (tid & 63)];
  // prior + invn per j (512 threads, 1 j each, 2 rows)
  {
    int j = tid;
    float4 cj0 = *(const float4*)(coords + j*NC);
    float4 cj1 = *(const float4*)(coords + j*NC + 4);
    #pragma unroll
    for (int r = 0; r < 2; ++r){
      int i = ip + r;
      float4 ci0 = *(const float4*)(coords + i*NC);
      float4 ci1 = *(const float4*)(coords + i*NC + 4);
      float dd = 0.f;
      dd = fmaf(ci0.x-cj0.x, ci0.x-cj0.x, dd);
      dd = fmaf(ci0.y-cj0.y, ci0.y-cj0.y, dd);
      dd = fmaf(ci0.z-cj0.z, ci0.z-cj0.z, dd);
      dd = fmaf(ci0.w-cj0.w, ci0.w-cj0.w, dd);
      dd = fmaf(ci1.x-cj1.x, ci1.x-cj1.x, dd);
      dd = fmaf(ci1.y-cj1.y, ci1.y-cj1.y, dd);
      dd = fmaf(ci1.z-cj1.z, ci1.z-cj1.z, dd);
      dd = fmaf(ci1.w-cj1.w, ci1.w-cj1.w, dd);
      float dist = sqrtf(fmaxf(dd, 1e-12f));
      s_pri[r][j] = (j == i) ? be2v : fmaf(spps, 1.f/(1.f + dist), be2v);
    }
    s_invn[j] = invn[b*NN + j];
  }
  __syncthreads();   // s_hi ready

  // B-frags in LDS: wa copy + per-row cw = f16(Wj + diag(hi)*Wp)
  {
    int frag = tid >> 6;          // 0..7 = ks*4+nt
    int l2   = tid & 63;
    const u4* wsrc = (const u4*)wa16;
    *(u4*)&lds_wa[(frag*64 + l2)*4] = wsrc[frag*64 + l2];

    int ch0 = (frag >> 2)*32 + (l2 >> 4)*8;
    const float* wj = wjf + (frag*64 + l2)*8;
    const float* wp = wpf + (frag*64 + l2)*8;
    #pragma unroll
    for (int r = 0; r < 2; ++r){
      u4 u;
      #pragma unroll
      for (int d = 0; d < 4; ++d){
        float v0 = fmaf(s_hi[r][ch0 + 2*d],     wp[2*d],     wj[2*d]);
        float v1 = fmaf(s_hi[r][ch0 + 2*d + 1], wp[2*d + 1], wj[2*d + 1]);
        u[d] = pkh(v0, v1);
      }
      *(u4*)&lds_cw[r][(frag*64 + l2)*4] = u;
    }
  }

  // per-lane hi packed f16 for both rows
  const u4* hfv = (const u4*)hf16;
  u4 hiA[2][2];
  #pragma unroll
  for (int r = 0; r < 2; ++r){
    hiA[r][0] = hfv[(b*NN + ip + r)*8 + kg];
    hiA[r][1] = hfv[(b*NN + ip + r)*8 + kg + 4];
  }

  float pv4[2][4], we2q[4];
  #pragma unroll
  for (int nt = 0; nt < 4; ++nt){
    #pragma unroll
    for (int r = 0; r < 2; ++r)
      pv4[r][nt] = pvec[(b*NN + ip + r)*64 + nt*16 + q];
    we2q[nt] = We2[nt*16 + q];
  }
  float invni[2];
  invni[0] = invn[b*NN + ip];
  invni[1] = invn[b*NN + ip + 1];
  int srcl = (lane & 48) | (((lane >> 4) & 3) << 2) | (lane & 3);
  __syncthreads();   // lds_wa / lds_cw ready

  unsigned* slice = &s_hj[w][0];
  const u4 absm = (u4){0x7fff7fffu, 0x7fff7fffu, 0x7fff7fffu, 0x7fff7fffu};

  #pragma unroll
  for (int s = 0; s < 4; ++s){
    int it = w + s*8;
    int jbase = it * 16;

    // stage hj tile (16 rows x 64 ch f16 = 2 KB) coalesced -> wave-private LDS
    {
      int r8 = lane >> 3, c8 = lane & 7;
      u4 g0 = *(const u4*)((const unsigned*)hf16 + (size_t)(b*NN + jbase + r8)*32 + c8*4);
      u4 g1 = *(const u4*)((const unsigned*)hf16 + (size_t)(b*NN + jbase + 8 + r8)*32 + c8*4);
      unsigned* p0 = slice + r8*34 + c8*4;
      unsigned* p1 = slice + (8 + r8)*34 + c8*4;
      u2 t;
      t.x = g0.x; t.y = g0.y; *(u2*)p0 = t;
      t.x = g0.z; t.y = g0.w; *(u2*)(p0 + 2) = t;
      t.x = g1.x; t.y = g1.y; *(u2*)p1 = t;
      t.x = g1.z; t.y = g1.w; *(u2*)(p1 + 2) = t;
    }

    // this lane's hj fragment (row q, k-slices kg)
    u4 hj0, hj1;
    {
      unsigned* rp = slice + q*34 + kg*4;
      u2 a0 = *(u2*)rp;
      u2 a1 = *(u2*)(rp + 2);
      u2 b0 = *(u2*)(rp + 16);
      u2 b1 = *(u2*)(rp + 18);
      hj0.x = a0.x; hj0.y = a0.y; hj0.z = a1.x; hj0.w = a1.y;
      hj1.x = b0.x; hj1.y = b0.y; hj1.z = b1.x; hj1.w = b1.y;
    }
    h8 hjv0 = __builtin_bit_cast(h8, hj0);
    h8 hjv1 = __builtin_bit_cast(h8, hj1);

    // inline per-lane f16 dot (for cos): 16 channels, both rows
    float dotp[2];
    #pragma unroll
    for (int r = 0; r < 2; ++r){
      float d0 = dot8(hiA[r][0], hj0, 0.f);
      dotp[r]  = dot8(hiA[r][1], hj1, d0);
    }

    f32x4 acc[2][4];
    #pragma unroll
    for (int r = 0; r < 2; ++r)
      #pragma unroll
      for (int nt = 0; nt < 4; ++nt)
        acc[r][nt] = (f32x4){pv4[r][nt], pv4[r][nt], pv4[r][nt], pv4[r][nt]};

    #pragma unroll
    for (int nt = 0; nt < 4; ++nt){
      h8 wA0 = __builtin_bit_cast(h8, *(const u4*)&lds_wa[((0*4 + nt)*64 + lane)*4]);
      h8 wA1 = __builtin_bit_cast(h8, *(const u4*)&lds_wa[((1*4 + nt)*64 + lane)*4]);
      #pragma unroll
      for (int r = 0; r < 2; ++r){
        h8 dh0 = __builtin_bit_cast(h8, hiA[r][0]) - hjv0;
        h8 dh1 = __builtin_bit_cast(h8, hiA[r][1]) - hjv1;
        h8 af0 = __builtin_bit_cast(h8, __builtin_bit_cast(u4, dh0) & absm);
        h8 af1 = __builtin_bit_cast(h8, __builtin_bit_cast(u4, dh1) & absm);
        h8 wC0 = __builtin_bit_cast(h8, *(const u4*)&lds_cw[r][((0*4 + nt)*64 + lane)*4]);
        h8 wC1 = __builtin_bit_cast(h8, *(const u4*)&lds_cw[r][((1*4 + nt)*64 + lane)*4]);
        acc[r][nt] = __builtin_amdgcn_mfma_f32_16x16x32_f16(af0, wA0, acc[r][nt], 0, 0, 0);
        acc[r][nt] = __builtin_amdgcn_mfma_f32_16x16x32_f16(af1, wA1, acc[r][nt], 0, 0, 0);
        acc[r][nt] = __builtin_amdgcn_mfma_f32_16x16x32_f16(hjv0, wC0, acc[r][nt], 0, 0, 0);
        acc[r][nt] = __builtin_amdgcn_mfma_f32_16x16x32_f16(hjv1, wC1, acc[r][nt], 0, 0, 0);
      }
    }

    // epilogue per row: relu + We2 dot, DPP reduce; add prior + cos
    #pragma unroll
    for (int r = 0; r < 2; ++r){
      float part[4] = {0.f, 0.f, 0.f, 0.f};
      #pragma unroll
      for (int nt = 0; nt < 4; ++nt)
        #pragma unroll
        for (int rr = 0; rr < 4; ++rr)
          part[rr] = fmaf(fmaxf(acc[r][nt][rr], 0.f), we2q[nt], part[rr]);
      #pragma unroll
      for (int rr = 0; rr < 4; ++rr) part[rr] = row16_sum(part[rr]);

      float dp = dotp[r];
      dp += __shfl_xor(dp, 16);
      dp += __shfl_xor(dp, 32);
      float dj = __shfl(dp, srcl);     // dot for j = jbase + kg*4 + (lane&3)

      if (q < 4){
        int j2 = jbase + kg*4 + q;
        float ps2 = part[0];
        ps2 = (q == 1) ? part[1] : ps2;
        ps2 = (q == 2) ? part[2] : ps2;
        ps2 = (q == 3) ? part[3] : ps2;
        float cosv = dj * invni[r] * s_invn[j2];
        lrow[r][j2] = ps2 + s_pri[r][j2] + spss * cosv;
      }
    }
  }
  __syncthreads();

  // fused dual-row softmax; diag override here
  float va = (tid == ip)     ? spsl : lrow[0][tid];
  float vb = (tid == ip + 1) ? spsl : lrow[1][tid];

  float ma = va, mb = vb;
  #pragma unroll
  for (int msk = 1; msk < 64; msk <<= 1){
    ma = fmaxf(ma, __shfl_xor(ma, msk));
    mb = fmaxf(mb, __shfl_xor(mb, msk));
  }
  if (lane == 0){ red[w] = ma; red[8 + w] = mb; }
  __syncthreads();
  ma = red[0]; mb = red[8];
  #pragma unroll
  for (int ww = 1; ww < 8; ++ww){
    ma = fmaxf(ma, red[ww]);
    mb = fmaxf(mb, red[8 + ww]);
  }

  float ea = expf((va - ma) * invt);
  float eb = expf((vb - mb) * invt);
  float sa = ea, sb = eb;
  #pragma unroll
  for (int msk = 1; msk < 64; msk <<= 1){
    sa += __shfl_xor(sa, msk);
    sb += __shfl_xor(sb, msk);
  }
  if (lane == 0){ red[16 + w] = sa; red[24 + w] = sb; }
  __syncthreads();
  sa = red[16]; sb = red[24];
  #pragma unroll
  for (int ww = 1; ww < 8; ++ww){
    sa += red[16 + ww];
    sb += red[24 + ww];
  }

  unsym[(size_t)(b*NN + ip)*NN + tid]       = ea / sa;
  unsym[(size_t)(b*NN + ip + 1)*NN + tid]   = eb / sb;
}

// ---------------- Kernel D: symmetrize + renormalize ----------------
__global__ __launch_bounds__(256) void k_sym(
    const float* __restrict__ u, float* __restrict__ out){
  int blk = blockIdx.x;
  int b = blk >> 9, i = blk & (NN-1);
  int tid = threadIdx.x;
  const float* urow = u + (size_t)(b*NN + i) * NN;
  float v0, v1, rs;
  {
    int j0 = tid, j1 = tid + 256;
    float a1 = urow[j0];
    float a2 = u[(size_t)(b*NN + j0) * NN + i];
    v0 = 0.5f*(a1 + a2);
    float a3 = urow[j1];
    float a4 = u[(size_t)(b*NN + j1) * NN + i];
    v1 = 0.5f*(a3 + a4);
    rs = v0 + v1;
  }
  int lane = tid & 63, w = tid >> 6;
  #pragma unroll
  for (int msk = 1; msk < 64; msk <<= 1) rs += __shfl_xor(rs, msk);
  __shared__ float red[4];
  if (lane == 0) red[w] = rs;
  __syncthreads();
  rs = red[0] + red[1] + red[2] + red[3];
  float inv = 1.f / fmaxf(rs, 1e-6f);
  float* orow = out + (size_t)(b*NN + i) * NN;
  orow[tid]       = v0 * inv;
  orow[tid + 256] = v1 * inv;
}

extern "C" void kernel_launch(void* const* d_in, const int* in_sizes, int n_in,
                              void* d_out, int out_size, void* d_ws, size_t ws_size,
                              hipStream_t stream){
  const float* x      = (const float*)d_in[0];
  const float* mask   = (const float*)d_in[1];
  const float* sctx   = (const float*)d_in[2];
  const float* coords = (const float*)d_in[3];
  const float* W1     = (const float*)d_in[4];
  const float* b1     = (const float*)d_in[5];
  const float* W2     = (const float*)d_in[6];
  const float* b2     = (const float*)d_in[7];
  const float* We1    = (const float*)d_in[8];
  const float* be1    = (const float*)d_in[9];
  const float* We2    = (const float*)d_in[10];
  const float* be2    = (const float*)d_in[11];
  const float* sl     = (const float*)d_in[12];
  const float* ps     = (const float*)d_in[13];
  const float* ss     = (const float*)d_in[14];
  const float* tp     = (const float*)d_in[15];

  float*    ws    = (float*)d_ws;
  float*    hgp   = ws + OFF_H;
  float*    pvecp = ws + OFF_PVEC;
  unsigned* hf16p = (unsigned*)(ws + OFF_HF16);
  float*    invnp = ws + OFF_INVN;
  short*    wa16p = (short*)(ws + OFF_WA16);
  float*    wjfp  = ws + OFF_WJF;
  float*    wpfp  = ws + OFF_WPF;
  float*    unsym = ws + OFF_UNSYM;
  float*    out   = (float*)d_out;

  k_front <<<304, 256, 0, stream>>>(x, mask, sctx, W1, b1, W2, b2, We1, be1,
                                    hgp, pvecp, hf16p, invnp, wa16p, wjfp, wpfp);
  k_logits<<<NB*NN/2, 512, 0, stream>>>(hgp, pvecp, hf16p, invnp, wa16p, wjfp,
                                        wpfp, coords, We2, be2, sl, ps, ss, tp,
                                        unsym);
  k_sym   <<<NB*NN, 256, 0, stream>>>(unsym, out);
}

// Round 18
// 42.873 us; speedup vs baseline: 1.2590x; 1.0140x over previous
//
#include <hip/hip_runtime.h>
#include <hip/hip_bf16.h>
#include <math.h>

#define NB 2
#define NT 256
#define NN 512
#define NH 64
#define NS 8
#define NC 8

// workspace layout (float offsets)
#define OFF_H      0          // 65536  h f32
#define OFF_PVEC   65536      // 65536  pre_i + be1
#define OFF_HF16   131072     // 32768 dwords: h packed f16
#define OFF_INVN   163840     // 1024
#define OFF_WA16   164864     // 2048 floats = 4096 f16 (Wa frags)
#define OFF_WJF    166912     // 4096 floats (Wj, frag order)
#define OFF_WPF    171008     // 4096 floats (Wp, frag order)
#define OFF_UNSYM  175104     // 524288

typedef __attribute__((ext_vector_type(8))) _Float16 h8;
typedef __attribute__((ext_vector_type(2))) __fp16 fp16x2;
typedef __attribute__((ext_vector_type(4))) float f32x4;
typedef __attribute__((ext_vector_type(4))) unsigned u4;
typedef __attribute__((ext_vector_type(2))) unsigned u2;

__device__ __forceinline__ float softplusf(float x){
  if (x > 20.f) return x;
  return log1pf(expf(x));
}

__device__ __forceinline__ unsigned pkh(float a, float b){
  fp16x2 h = __builtin_amdgcn_cvt_pkrtz(a, b);
  return __builtin_bit_cast(unsigned, h);
}

// f32 += dot of packed f16 pairs
__device__ __forceinline__ float fdot2u(unsigned a, unsigned b, float c){
#if __has_builtin(__builtin_amdgcn_fdot2)
  return __builtin_amdgcn_fdot2(__builtin_bit_cast(fp16x2, a),
                                __builtin_bit_cast(fp16x2, b), c, false);
#else
  fp16x2 av = __builtin_bit_cast(fp16x2, a);
  fp16x2 bv = __builtin_bit_cast(fp16x2, b);
  return fmaf((float)av.x, (float)bv.x, fmaf((float)av.y, (float)bv.y, c));
#endif
}
__device__ __forceinline__ float dot8(u4 a, u4 b, float acc){
  #pragma unroll
  for (int d = 0; d < 4; ++d) acc = fdot2u(a[d], b[d], acc);
  return acc;
}

template<int CTRL>
__device__ __forceinline__ float dpp_addf(float x){
  int xi = __builtin_bit_cast(int, x);
  int yi = __builtin_amdgcn_update_dpp(0, xi, CTRL, 0xF, 0xF, true);
  return x + __builtin_bit_cast(float, yi);
}
__device__ __forceinline__ float row16_sum(float x){
  x = dpp_addf<0xB1>(x);    // lane^1
  x = dpp_addf<0x4E>(x);    // lane^2
  x = dpp_addf<0x141>(x);   // lane^7
  x = dpp_addf<0x140>(x);   // lane^15
  return x;
}

// ---------------- Kernel FRONT: stats + node MLP + weight prep ----------------
__global__ __launch_bounds__(256) void k_front(
    const float* __restrict__ x, const float* __restrict__ mask,
    const float* __restrict__ sctx,
    const float* __restrict__ W1, const float* __restrict__ b1,
    const float* __restrict__ W2, const float* __restrict__ b2,
    const float* __restrict__ We1, const float* __restrict__ be1,
    float* __restrict__ hg, float* __restrict__ pvec,
    unsigned* __restrict__ hf16, float* __restrict__ invn,
    short* __restrict__ wa16, float* __restrict__ wjf,
    float* __restrict__ wpf){
  int blk = blockIdx.x;
  int tid = threadIdx.x;

  if (blk >= 256){
    int pidx = (blk - 256)*256 + tid;        // 0..12287
    int e    = pidx & 7;
    int lane = (pidx >> 3) & 63;
    int frag = (pidx >> 9) & 7;              // ks*4+nt
    int nt = frag & 3, ks = frag >> 2;
    int kg = lane >> 4, q = lane & 15;
    int kk = ks*32 + kg*8 + e;
    int c  = nt*16 + q;
    if (pidx < 4096){
      _Float16 v = (_Float16)We1[(128 + kk)*NH + c];       // Wa rows 128..191
      wa16[pidx] = __builtin_bit_cast(short, v);
    } else if (pidx < 8192){
      wjf[pidx - 4096] = We1[(64 + kk)*NH + c];            // Wj rows 64..127
    } else {
      wpf[pidx - 8192] = We1[(192 + kk)*NH + c];           // Wp rows 192..255
    }
    return;
  }

  int b  = blk >> 7;
  int n0 = (blk & 127) * 4;

  // ---- stats: 4 nl x 64 ts ----
  int nl = tid & 3;
  int ts = tid >> 2;
  int n  = n0 + nl;

  float cnt = 0.f, sx = 0.f, sxx = 0.f;
  int lastt = 0;
  for (int t = ts*4; t < ts*4 + 4; ++t){
    int idx = (b*NT + t)*NN + n;
    float xv = x[idx];
    float mv = mask[idx];
    bool obs = (mv < 0.5f);
    if (obs){ cnt += 1.f; sx += xv; sxx += xv*xv; lastt = t; }
  }
  #pragma unroll
  for (int m = 4; m < 64; m <<= 1){
    cnt   += __shfl_xor(cnt,  m);
    sx    += __shfl_xor(sx,   m);
    sxx   += __shfl_xor(sxx,  m);
    lastt  = max(lastt, __shfl_xor(lastt, m));
  }
  int w = tid >> 6;
  __shared__ float r_cnt[4][4], r_sx[4][4], r_sxx[4][4];
  __shared__ int   r_lt[4][4];
  __shared__ float s_dyn[4][4];
  if ((tid & 63) < 4){
    r_cnt[w][nl] = cnt; r_sx[w][nl] = sx; r_sxx[w][nl] = sxx; r_lt[w][nl] = lastt;
  }
  __syncthreads();
  if (tid < 4){
    float c = 0.f, s1 = 0.f, s2 = 0.f; int lt = 0;
    #pragma unroll
    for (int ww = 0; ww < 4; ++ww){
      c  += r_cnt[ww][tid]; s1 += r_sx[ww][tid]; s2 += r_sxx[ww][tid];
      lt  = max(lt, r_lt[ww][tid]);
    }
    float cc   = fmaxf(c, 1.f);
    float mean = s1 / cc;
    float var  = s2 / cc - mean*mean;
    float stdv = sqrtf(fmaxf(var, 0.f) + 1e-6f);
    float last = x[(b*NT + lt)*NN + n0 + tid];
    float mr   = 1.f - c * (1.f/(float)NT);
    s_dyn[tid][0] = mean; s_dyn[tid][1] = stdv; s_dyn[tid][2] = last; s_dyn[tid][3] = mr;
  }
  __syncthreads();

  // ---- node MLP: wave w = node n0+w, lane c = channel ----
  int c = tid & 63;
  int gn = n0 + w;
  int bn = b*NN + gn;
  __shared__ float s_f[4][12];
  __shared__ float s_h1[4][64];
  __shared__ float s_h2[4][64];

  if (c < 4)       s_f[w][c] = s_dyn[w][c];
  else if (c < 12) s_f[w][c] = sctx[gn*NS + (c-4)];
  __syncthreads();

  float a = b1[c];
  #pragma unroll
  for (int k = 0; k < 12; ++k) a = fmaf(s_f[w][k], W1[k*NH + c], a);
  s_h1[w][c] = fmaxf(a, 0.f);
  __syncthreads();

  float a2 = b2[c];
  #pragma unroll 8
  for (int k = 0; k < 64; ++k) a2 = fmaf(s_h1[w][k], W2[k*NH + c], a2);
  a2 = fmaxf(a2, 0.f);

  float sq = a2*a2;
  #pragma unroll
  for (int m = 1; m < 64; m <<= 1) sq += __shfl_xor(sq, m);
  float inv = 1.f / fmaxf(sqrtf(sq), 1e-12f);

  s_h2[w][c] = a2;
  __syncthreads();

  float pi = be1[c];
  #pragma unroll 8
  for (int k = 0; k < 64; ++k) pi = fmaf(s_h2[w][k], We1[k*NH + c], pi);  // Wi

  hg  [bn*64 + c] = a2;
  pvec[bn*64 + c] = pi;
  if (c < 32){
    float e0 = s_h2[w][2*c], e1 = s_h2[w][2*c + 1];
    hf16[bn*32 + c] = pkh(e0, e1);
  }
  if (c == 0) invn[bn] = inv;
}

// ---------------- Kernel LOGITS: 2 i-rows/block + T14 prefetch + softmax -----
// grid NB*NN/2, 512 thr = 8 waves; wave: 4 j-tiles (double-buffered LDS slice,
// next tile's global loads issued before current compute).
__global__ __launch_bounds__(512, 4) void k_logits(
    const float* __restrict__ hg, const float* __restrict__ pvec,
    const unsigned* __restrict__ hf16, const float* __restrict__ invn,
    const short* __restrict__ wa16, const float* __restrict__ wjf,
    const float* __restrict__ wpf, const float* __restrict__ coords,
    const float* __restrict__ We2, const float* __restrict__ be2,
    const float* __restrict__ s_sl, const float* __restrict__ s_ps,
    const float* __restrict__ s_ss, const float* __restrict__ s_tp,
    float* __restrict__ unsym){
  int blk = blockIdx.x;
  int b  = blk >> 8;
  int ip = (blk & 255) * 2;          // rows ip, ip+1
  int tid  = threadIdx.x;
  int w    = tid >> 6;
  int lane = tid & 63;
  int q    = lane & 15;
  int kg   = lane >> 4;

  __shared__ __align__(16) float s_hi[2][64];
  __shared__ __align__(16) float s_pri[2][NN];     // be2 + spps*prior
  __shared__ __align__(16) float s_invn[NN];
  __shared__ __align__(16) float lrow[2][NN];
  __shared__ __align__(16) unsigned lds_wa[2048];  // 8 frags x 64 x 4dw
  __shared__ __align__(16) unsigned lds_cw[2][2048];
  __shared__ __align__(16) unsigned s_hj[8][2][16*34 + 2];  // dbuf per wave
  __shared__ float red[32];

  float spsl = softplusf(s_sl[0]);
  float spps = softplusf(s_ps[0]);
  float spss = softplusf(s_ss[0]);
  float invt = 1.f / (softplusf(s_tp[0]) + 1e-4f);
  float be2v = be2[0];

  if (tid < 128)
    s_hi[tid >> 6][tid & 63] = hg[(b*NN + ip + (tid >> 6))*64 + (tid & 63)];
  // prior + invn per j (512 threads, 1 j each, 2 rows)
  {
    int j = tid;
    float4 cj0 = *(const float4*)(coords + j*NC);
    float4 cj1 = *(const float4*)(coords + j*NC + 4);
    #pragma unroll
    for (int r = 0; r < 2; ++r){
      int i = ip + r;
      float4 ci0 = *(const float4*)(coords + i*NC);
      float4 ci1 = *(const float4*)(coords + i*NC + 4);
      float dd = 0.f;
      dd = fmaf(ci0.x-cj0.x, ci0.x-cj0.x, dd);
      dd = fmaf(ci0.y-cj0.y, ci0.y-cj0.y, dd);
      dd = fmaf(ci0.z-cj0.z, ci0.z-cj0.z, dd);
      dd = fmaf(ci0.w-cj0.w, ci0.w-cj0.w, dd);
      dd = fmaf(ci1.x-cj1.x, ci1.x-cj1.x, dd);
      dd = fmaf(ci1.y-cj1.y, ci1.y-cj1.y, dd);
      dd = fmaf(ci1.z-cj1.z, ci1.z-cj1.z, dd);
      dd = fmaf(ci1.w-cj1.w, ci1.w-cj1.w, dd);
      float dist = sqrtf(fmaxf(dd, 1e-12f));
      s_pri[r][j] = (j == i) ? be2v : fmaf(spps, 1.f/(1.f + dist), be2v);
    }
    s_invn[j] = invn[b*NN + j];
  }
  __syncthreads();   // s_hi ready

  // B-frags in LDS: wa copy + per-row cw = f16(Wj + diag(hi)*Wp)
  {
    int frag = tid >> 6;          // 0..7 = ks*4+nt
    int l2   = tid & 63;
    const u4* wsrc = (const u4*)wa16;
    *(u4*)&lds_wa[(frag*64 + l2)*4] = wsrc[frag*64 + l2];

    int ch0 = (frag >> 2)*32 + (l2 >> 4)*8;
    const float* wj = wjf + (frag*64 + l2)*8;
    const float* wp = wpf + (frag*64 + l2)*8;
    #pragma unroll
    for (int r = 0; r < 2; ++r){
      u4 u;
      #pragma unroll
      for (int d = 0; d < 4; ++d){
        float v0 = fmaf(s_hi[r][ch0 + 2*d],     wp[2*d],     wj[2*d]);
        float v1 = fmaf(s_hi[r][ch0 + 2*d + 1], wp[2*d + 1], wj[2*d + 1]);
        u[d] = pkh(v0, v1);
      }
      *(u4*)&lds_cw[r][(frag*64 + l2)*4] = u;
    }
  }

  // per-lane hi packed f16 for both rows
  const u4* hfv = (const u4*)hf16;
  u4 hiA[2][2];
  #pragma unroll
  for (int r = 0; r < 2; ++r){
    hiA[r][0] = hfv[(b*NN + ip + r)*8 + kg];
    hiA[r][1] = hfv[(b*NN + ip + r)*8 + kg + 4];
  }

  float pv4[2][4], we2q[4];
  #pragma unroll
  for (int nt = 0; nt < 4; ++nt){
    #pragma unroll
    for (int r = 0; r < 2; ++r)
      pv4[r][nt] = pvec[(b*NN + ip + r)*64 + nt*16 + q];
    we2q[nt] = We2[nt*16 + q];
  }
  float invni[2];
  invni[0] = invn[b*NN + ip];
  invni[1] = invn[b*NN + ip + 1];
  int srcl = (lane & 48) | (((lane >> 4) & 3) << 2) | (lane & 3);
  int r8 = lane >> 3, c8 = lane & 7;
  __syncthreads();   // lds_wa / lds_cw ready

  const u4 absm = (u4){0x7fff7fffu, 0x7fff7fffu, 0x7fff7fffu, 0x7fff7fffu};

  // prefetch tile s=0 into regs
  u4 g0, g1;
  {
    int jbase = w * 16;
    g0 = *(const u4*)((const unsigned*)hf16 + (size_t)(b*NN + jbase + r8)*32 + c8*4);
    g1 = *(const u4*)((const unsigned*)hf16 + (size_t)(b*NN + jbase + 8 + r8)*32 + c8*4);
  }

  #pragma unroll
  for (int s = 0; s < 4; ++s){
    int jbase = (w + s*8) * 16;
    unsigned* slice = &s_hj[w][s & 1][0];

    // write current tile's staged regs to this wave's LDS slice
    {
      unsigned* p0 = slice + r8*34 + c8*4;
      unsigned* p1 = slice + (8 + r8)*34 + c8*4;
      u2 t;
      t.x = g0.x; t.y = g0.y; *(u2*)p0 = t;
      t.x = g0.z; t.y = g0.w; *(u2*)(p0 + 2) = t;
      t.x = g1.x; t.y = g1.y; *(u2*)p1 = t;
      t.x = g1.z; t.y = g1.w; *(u2*)(p1 + 2) = t;
    }
    // issue next tile's global loads (overlap with this tile's compute)
    if (s < 3){
      int jn = (w + (s+1)*8) * 16;
      g0 = *(const u4*)((const unsigned*)hf16 + (size_t)(b*NN + jn + r8)*32 + c8*4);
      g1 = *(const u4*)((const unsigned*)hf16 + (size_t)(b*NN + jn + 8 + r8)*32 + c8*4);
    }

    // this lane's hj fragment (row q, k-slices kg)
    u4 hj0, hj1;
    {
      unsigned* rp = slice + q*34 + kg*4;
      u2 a0 = *(u2*)rp;
      u2 a1 = *(u2*)(rp + 2);
      u2 b0 = *(u2*)(rp + 16);
      u2 b1 = *(u2*)(rp + 18);
      hj0.x = a0.x; hj0.y = a0.y; hj0.z = a1.x; hj0.w = a1.y;
      hj1.x = b0.x; hj1.y = b0.y; hj1.z = b1.x; hj1.w = b1.y;
    }
    h8 hjv0 = __builtin_bit_cast(h8, hj0);
    h8 hjv1 = __builtin_bit_cast(h8, hj1);

    // inline per-lane f16 dot (for cos): 16 channels, both rows
    float dotp[2];
    #pragma unroll
    for (int r = 0; r < 2; ++r){
      float d0 = dot8(hiA[r][0], hj0, 0.f);
      dotp[r]  = dot8(hiA[r][1], hj1, d0);
    }

    f32x4 acc[2][4];
    #pragma unroll
    for (int r = 0; r < 2; ++r)
      #pragma unroll
      for (int nt = 0; nt < 4; ++nt)
        acc[r][nt] = (f32x4){pv4[r][nt], pv4[r][nt], pv4[r][nt], pv4[r][nt]};

    #pragma unroll
    for (int nt = 0; nt < 4; ++nt){
      h8 wA0 = __builtin_bit_cast(h8, *(const u4*)&lds_wa[((0*4 + nt)*64 + lane)*4]);
      h8 wA1 = __builtin_bit_cast(h8, *(const u4*)&lds_wa[((1*4 + nt)*64 + lane)*4]);
      #pragma unroll
      for (int r = 0; r < 2; ++r){
        h8 dh0 = __builtin_bit_cast(h8, hiA[r][0]) - hjv0;
        h8 dh1 = __builtin_bit_cast(h8, hiA[r][1]) - hjv1;
        h8 af0 = __builtin_bit_cast(h8, __builtin_bit_cast(u4, dh0) & absm);
        h8 af1 = __builtin_bit_cast(h8, __builtin_bit_cast(u4, dh1) & absm);
        h8 wC0 = __builtin_bit_cast(h8, *(const u4*)&lds_cw[r][((0*4 + nt)*64 + lane)*4]);
        h8 wC1 = __builtin_bit_cast(h8, *(const u4*)&lds_cw[r][((1*4 + nt)*64 + lane)*4]);
        acc[r][nt] = __builtin_amdgcn_mfma_f32_16x16x32_f16(af0, wA0, acc[r][nt], 0, 0, 0);
        acc[r][nt] = __builtin_amdgcn_mfma_f32_16x16x32_f16(af1, wA1, acc[r][nt], 0, 0, 0);
        acc[r][nt] = __builtin_amdgcn_mfma_f32_16x16x32_f16(hjv0, wC0, acc[r][nt], 0, 0, 0);
        acc[r][nt] = __builtin_amdgcn_mfma_f32_16x16x32_f16(hjv1, wC1, acc[r][nt], 0, 0, 0);
      }
    }

    // epilogue per row: relu + We2 dot, DPP reduce; add prior + cos
    #pragma unroll
    for (int r = 0; r < 2; ++r){
      float part[4] = {0.f, 0.f, 0.f, 0.f};
      #pragma unroll
      for (int nt = 0; nt < 4; ++nt)
        #pragma unroll
        for (int rr = 0; rr < 4; ++rr)
          part[rr] = fmaf(fmaxf(acc[r][nt][rr], 0.f), we2q[nt], part[rr]);
      #pragma unroll
      for (int rr = 0; rr < 4; ++rr) part[rr] = row16_sum(part[rr]);

      float dp = dotp[r];
      dp += __shfl_xor(dp, 16);
      dp += __shfl_xor(dp, 32);
      float dj = __shfl(dp, srcl);     // dot for j = jbase + kg*4 + (lane&3)

      if (q < 4){
        int j2 = jbase + kg*4 + q;
        float ps2 = part[0];
        ps2 = (q == 1) ? part[1] : ps2;
        ps2 = (q == 2) ? part[2] : ps2;
        ps2 = (q == 3) ? part[3] : ps2;
        float cosv = dj * invni[r] * s_invn[j2];
        lrow[r][j2] = ps2 + s_pri[r][j2] + spss * cosv;
      }
    }
  }
  __syncthreads();

  // fused dual-row softmax; diag override here
  float va = (tid == ip)     ? spsl : lrow[0][tid];
  float vb = (tid == ip + 1) ? spsl : lrow[1][tid];

  float ma = va, mb = vb;
  #pragma unroll
  for (int msk = 1; msk < 64; msk <<= 1){
    ma = fmaxf(ma, __shfl_xor(ma, msk));
    mb = fmaxf(mb, __shfl_xor(mb, msk));
  }
  if (lane == 0){ red[w] = ma; red[8 + w] = mb; }
  __syncthreads();
  ma = red[0]; mb = red[8];
  #pragma unroll
  for (int ww = 1; ww < 8; ++ww){
    ma = fmaxf(ma, red[ww]);
    mb = fmaxf(mb, red[8 + ww]);
  }

  float ea = expf((va - ma) * invt);
  float eb = expf((vb - mb) * invt);
  float sa = ea, sb = eb;
  #pragma unroll
  for (int msk = 1; msk < 64; msk <<= 1){
    sa += __shfl_xor(sa, msk);
    sb += __shfl_xor(sb, msk);
  }
  if (lane == 0){ red[16 + w] = sa; red[24 + w] = sb; }
  __syncthreads();
  sa = red[16]; sb = red[24];
  #pragma unroll
  for (int ww = 1; ww < 8; ++ww){
    sa += red[16 + ww];
    sb += red[24 + ww];
  }

  unsym[(size_t)(b*NN + ip)*NN + tid]       = ea / sa;
  unsym[(size_t)(b*NN + ip + 1)*NN + tid]   = eb / sb;
}

// ---------------- Kernel D: symmetrize + renormalize (2 rows/block) ----------
__global__ __launch_bounds__(512) void k_sym(
    const float* __restrict__ u, float* __restrict__ out){
  int blk = blockIdx.x;
  int b  = blk >> 8;
  int ip = (blk & 255) * 2;
  int tid  = threadIdx.x;
  int lane = tid & 63, w = tid >> 6;

  const float* ra = u + (size_t)(b*NN + ip) * NN;
  const float* rb = u + (size_t)(b*NN + ip + 1) * NN;
  float2 colv = *(const float2*)(u + (size_t)(b*NN + tid)*NN + ip);
  float va = 0.5f*(ra[tid] + colv.x);
  float vb = 0.5f*(rb[tid] + colv.y);

  float sa = va, sb = vb;
  #pragma unroll
  for (int msk = 1; msk < 64; msk <<= 1){
    sa += __shfl_xor(sa, msk);
    sb += __shfl_xor(sb, msk);
  }
  __shared__ float red[16];
  if (lane == 0){ red[w] = sa; red[8 + w] = sb; }
  __syncthreads();
  sa = red[0]; sb = red[8];
  #pragma unroll
  for (int ww = 1; ww < 8; ++ww){
    sa += red[ww];
    sb += red[8 + ww];
  }
  float ia = 1.f / fmaxf(sa, 1e-6f);
  float ib = 1.f / fmaxf(sb, 1e-6f);
  out[(size_t)(b*NN + ip)*NN + tid]     = va * ia;
  out[(size_t)(b*NN + ip + 1)*NN + tid] = vb * ib;
}

extern "C" void kernel_launch(void* const* d_in, const int* in_sizes, int n_in,
                              void* d_out, int out_size, void* d_ws, size_t ws_size,
                              hipStream_t stream){
  const float* x      = (const float*)d_in[0];
  const float* mask   = (const float*)d_in[1];
  const float* sctx   = (const float*)d_in[2];
  const float* coords = (const float*)d_in[3];
  const float* W1     = (const float*)d_in[4];
  const float* b1     = (const float*)d_in[5];
  const float* W2     = (const float*)d_in[6];
  const float* b2     = (const float*)d_in[7];
  const float* We1    = (const float*)d_in[8];
  const float* be1    = (const float*)d_in[9];
  const float* We2    = (const float*)d_in[10];
  const float* be2    = (const float*)d_in[11];
  const float* sl     = (const float*)d_in[12];
  const float* ps     = (const float*)d_in[13];
  const float* ss     = (const float*)d_in[14];
  const float* tp     = (const float*)d_in[15];

  float*    ws    = (float*)d_ws;
  float*    hgp   = ws + OFF_H;
  float*    pvecp = ws + OFF_PVEC;
  unsigned* hf16p = (unsigned*)(ws + OFF_HF16);
  float*    invnp = ws + OFF_INVN;
  short*    wa16p = (short*)(ws + OFF_WA16);
  float*    wjfp  = ws + OFF_WJF;
  float*    wpfp  = ws + OFF_WPF;
  float*    unsym = ws + OFF_UNSYM;
  float*    out   = (float*)d_out;

  k_front <<<304, 256, 0, stream>>>(x, mask, sctx, W1, b1, W2, b2, We1, be1,
                                    hgp, pvecp, hf16p, invnp, wa16p, wjfp, wpfp);
  k_logits<<<NB*NN/2, 512, 0, stream>>>(hgp, pvecp, hf16p, invnp, wa16p, wjfp,
                                        wpfp, coords, We2, be2, sl, ps, ss, tp,
                                        unsym);
  k_sym   <<<NB*NN/2, 512, 0, stream>>>(unsym, out);
}

// Round 19
// 39.927 us; speedup vs baseline: 1.3519x; 1.0738x over previous
//
#include <hip/hip_runtime.h>
#include <hip/hip_bf16.h>
#include <math.h>

#define NB 2
#define NT 256
#define NN 512
#define NH 64
#define NS 8
#define NC 8

// workspace layout (float offsets)
#define OFF_H      0          // 65536  h f32
#define OFF_PVEC   65536      // 65536  pre_i + be1
#define OFF_HF16   131072     // 32768 dwords: h packed f16
#define OFF_INVN   163840     // 1024
#define OFF_WA16   164864     // 2048 floats = 4096 f16 (Wa frags)
#define OFF_WJF    166912     // 4096 floats (Wj, frag order)
#define OFF_WPF    171008     // 4096 floats (Wp, frag order)
#define OFF_UNSYM  175104     // 524288
#define OFF_UNSYMT (175104 + 524288)   // 524288 (transposed copy)

typedef __attribute__((ext_vector_type(8))) _Float16 h8;
typedef __attribute__((ext_vector_type(2))) __fp16 fp16x2;
typedef __attribute__((ext_vector_type(4))) float f32x4;
typedef __attribute__((ext_vector_type(4))) unsigned u4;
typedef __attribute__((ext_vector_type(2))) unsigned u2;

__device__ __forceinline__ float softplusf(float x){
  if (x > 20.f) return x;
  return log1pf(expf(x));
}

__device__ __forceinline__ unsigned pkh(float a, float b){
  fp16x2 h = __builtin_amdgcn_cvt_pkrtz(a, b);
  return __builtin_bit_cast(unsigned, h);
}

// f32 += dot of packed f16 pairs
__device__ __forceinline__ float fdot2u(unsigned a, unsigned b, float c){
#if __has_builtin(__builtin_amdgcn_fdot2)
  return __builtin_amdgcn_fdot2(__builtin_bit_cast(fp16x2, a),
                                __builtin_bit_cast(fp16x2, b), c, false);
#else
  fp16x2 av = __builtin_bit_cast(fp16x2, a);
  fp16x2 bv = __builtin_bit_cast(fp16x2, b);
  return fmaf((float)av.x, (float)bv.x, fmaf((float)av.y, (float)bv.y, c));
#endif
}
__device__ __forceinline__ float dot8(u4 a, u4 b, float acc){
  #pragma unroll
  for (int d = 0; d < 4; ++d) acc = fdot2u(a[d], b[d], acc);
  return acc;
}

template<int CTRL>
__device__ __forceinline__ float dpp_addf(float x){
  int xi = __builtin_bit_cast(int, x);
  int yi = __builtin_amdgcn_update_dpp(0, xi, CTRL, 0xF, 0xF, true);
  return x + __builtin_bit_cast(float, yi);
}
__device__ __forceinline__ float row16_sum(float x){
  x = dpp_addf<0xB1>(x);    // lane^1
  x = dpp_addf<0x4E>(x);    // lane^2
  x = dpp_addf<0x141>(x);   // lane^7
  x = dpp_addf<0x140>(x);   // lane^15
  return x;
}

// ---------------- Kernel FRONT: stats + node MLP + weight prep ----------------
__global__ __launch_bounds__(256) void k_front(
    const float* __restrict__ x, const float* __restrict__ mask,
    const float* __restrict__ sctx,
    const float* __restrict__ W1, const float* __restrict__ b1,
    const float* __restrict__ W2, const float* __restrict__ b2,
    const float* __restrict__ We1, const float* __restrict__ be1,
    float* __restrict__ hg, float* __restrict__ pvec,
    unsigned* __restrict__ hf16, float* __restrict__ invn,
    short* __restrict__ wa16, float* __restrict__ wjf,
    float* __restrict__ wpf){
  int blk = blockIdx.x;
  int tid = threadIdx.x;

  if (blk >= 256){
    int pidx = (blk - 256)*256 + tid;        // 0..12287
    int e    = pidx & 7;
    int lane = (pidx >> 3) & 63;
    int frag = (pidx >> 9) & 7;              // ks*4+nt
    int nt = frag & 3, ks = frag >> 2;
    int kg = lane >> 4, q = lane & 15;
    int kk = ks*32 + kg*8 + e;
    int c  = nt*16 + q;
    if (pidx < 4096){
      _Float16 v = (_Float16)We1[(128 + kk)*NH + c];       // Wa rows 128..191
      wa16[pidx] = __builtin_bit_cast(short, v);
    } else if (pidx < 8192){
      wjf[pidx - 4096] = We1[(64 + kk)*NH + c];            // Wj rows 64..127
    } else {
      wpf[pidx - 8192] = We1[(192 + kk)*NH + c];           // Wp rows 192..255
    }
    return;
  }

  int b  = blk >> 7;
  int n0 = (blk & 127) * 4;

  // ---- stats: 4 nl x 64 ts ----
  int nl = tid & 3;
  int ts = tid >> 2;
  int n  = n0 + nl;

  float cnt = 0.f, sx = 0.f, sxx = 0.f;
  int lastt = 0;
  for (int t = ts*4; t < ts*4 + 4; ++t){
    int idx = (b*NT + t)*NN + n;
    float xv = x[idx];
    float mv = mask[idx];
    bool obs = (mv < 0.5f);
    if (obs){ cnt += 1.f; sx += xv; sxx += xv*xv; lastt = t; }
  }
  #pragma unroll
  for (int m = 4; m < 64; m <<= 1){
    cnt   += __shfl_xor(cnt,  m);
    sx    += __shfl_xor(sx,   m);
    sxx   += __shfl_xor(sxx,  m);
    lastt  = max(lastt, __shfl_xor(lastt, m));
  }
  int w = tid >> 6;
  __shared__ float r_cnt[4][4], r_sx[4][4], r_sxx[4][4];
  __shared__ int   r_lt[4][4];
  __shared__ float s_dyn[4][4];
  if ((tid & 63) < 4){
    r_cnt[w][nl] = cnt; r_sx[w][nl] = sx; r_sxx[w][nl] = sxx; r_lt[w][nl] = lastt;
  }
  __syncthreads();
  if (tid < 4){
    float c = 0.f, s1 = 0.f, s2 = 0.f; int lt = 0;
    #pragma unroll
    for (int ww = 0; ww < 4; ++ww){
      c  += r_cnt[ww][tid]; s1 += r_sx[ww][tid]; s2 += r_sxx[ww][tid];
      lt  = max(lt, r_lt[ww][tid]);
    }
    float cc   = fmaxf(c, 1.f);
    float mean = s1 / cc;
    float var  = s2 / cc - mean*mean;
    float stdv = sqrtf(fmaxf(var, 0.f) + 1e-6f);
    float last = x[(b*NT + lt)*NN + n0 + tid];
    float mr   = 1.f - c * (1.f/(float)NT);
    s_dyn[tid][0] = mean; s_dyn[tid][1] = stdv; s_dyn[tid][2] = last; s_dyn[tid][3] = mr;
  }
  __syncthreads();

  // ---- node MLP: wave w = node n0+w, lane c = channel ----
  int c = tid & 63;
  int gn = n0 + w;
  int bn = b*NN + gn;
  __shared__ float s_f[4][12];
  __shared__ float s_h1[4][64];
  __shared__ float s_h2[4][64];

  if (c < 4)       s_f[w][c] = s_dyn[w][c];
  else if (c < 12) s_f[w][c] = sctx[gn*NS + (c-4)];
  __syncthreads();

  float a = b1[c];
  #pragma unroll
  for (int k = 0; k < 12; ++k) a = fmaf(s_f[w][k], W1[k*NH + c], a);
  s_h1[w][c] = fmaxf(a, 0.f);
  __syncthreads();

  // 4-way split accumulators (shorten dependent fma chain 64 -> 16)
  float t0 = 0.f, t1 = 0.f, t2 = 0.f, t3 = 0.f;
  #pragma unroll 4
  for (int k = 0; k < 64; k += 4){
    t0 = fmaf(s_h1[w][k],     W2[(k)*NH + c],     t0);
    t1 = fmaf(s_h1[w][k + 1], W2[(k + 1)*NH + c], t1);
    t2 = fmaf(s_h1[w][k + 2], W2[(k + 2)*NH + c], t2);
    t3 = fmaf(s_h1[w][k + 3], W2[(k + 3)*NH + c], t3);
  }
  float a2 = b2[c] + ((t0 + t1) + (t2 + t3));
  a2 = fmaxf(a2, 0.f);

  float sq = a2*a2;
  #pragma unroll
  for (int m = 1; m < 64; m <<= 1) sq += __shfl_xor(sq, m);
  float inv = 1.f / fmaxf(sqrtf(sq), 1e-12f);

  s_h2[w][c] = a2;
  __syncthreads();

  float p0 = 0.f, p1 = 0.f, p2 = 0.f, p3 = 0.f;
  #pragma unroll 4
  for (int k = 0; k < 64; k += 4){
    p0 = fmaf(s_h2[w][k],     We1[(k)*NH + c],     p0);
    p1 = fmaf(s_h2[w][k + 1], We1[(k + 1)*NH + c], p1);
    p2 = fmaf(s_h2[w][k + 2], We1[(k + 2)*NH + c], p2);
    p3 = fmaf(s_h2[w][k + 3], We1[(k + 3)*NH + c], p3);
  }
  float pi = be1[c] + ((p0 + p1) + (p2 + p3));   // Wi rows 0..63

  hg  [bn*64 + c] = a2;
  pvec[bn*64 + c] = pi;
  if (c < 32){
    float e0 = s_h2[w][2*c], e1 = s_h2[w][2*c + 1];
    hf16[bn*32 + c] = pkh(e0, e1);
  }
  if (c == 0) invn[bn] = inv;
}

// ---------------- Kernel LOGITS: 2 i-rows/block + T14 prefetch + softmax -----
// Also emits the transposed adjacency copy (unsymT[j][i] = unsym[i][j]) so
// k_sym never does a strided column gather.
__global__ __launch_bounds__(512, 4) void k_logits(
    const float* __restrict__ hg, const float* __restrict__ pvec,
    const unsigned* __restrict__ hf16, const float* __restrict__ invn,
    const short* __restrict__ wa16, const float* __restrict__ wjf,
    const float* __restrict__ wpf, const float* __restrict__ coords,
    const float* __restrict__ We2, const float* __restrict__ be2,
    const float* __restrict__ s_sl, const float* __restrict__ s_ps,
    const float* __restrict__ s_ss, const float* __restrict__ s_tp,
    float* __restrict__ unsym, float* __restrict__ unsymT){
  int blk = blockIdx.x;
  int b  = blk >> 8;
  int ip = (blk & 255) * 2;          // rows ip, ip+1
  int tid  = threadIdx.x;
  int w    = tid >> 6;
  int lane = tid & 63;
  int q    = lane & 15;
  int kg   = lane >> 4;

  __shared__ __align__(16) float s_hi[2][64];
  __shared__ __align__(16) float s_pri[2][NN];     // be2 + spps*prior
  __shared__ __align__(16) float s_invn[NN];
  __shared__ __align__(16) float lrow[2][NN];
  __shared__ __align__(16) unsigned lds_wa[2048];  // 8 frags x 64 x 4dw
  __shared__ __align__(16) unsigned lds_cw[2][2048];
  __shared__ __align__(16) unsigned s_hj[8][2][16*34 + 2];  // dbuf per wave
  __shared__ float red[32];

  float spsl = softplusf(s_sl[0]);
  float spps = softplusf(s_ps[0]);
  float spss = softplusf(s_ss[0]);
  float invt = 1.f / (softplusf(s_tp[0]) + 1e-4f);
  float be2v = be2[0];

  if (tid < 128)
    s_hi[tid >> 6][tid & 63] = hg[(b*NN + ip + (tid >> 6))*64 + (tid & 63)];
  // prior + invn per j (512 threads, 1 j each, 2 rows)
  {
    int j = tid;
    float4 cj0 = *(const float4*)(coords + j*NC);
    float4 cj1 = *(const float4*)(coords + j*NC + 4);
    #pragma unroll
    for (int r = 0; r < 2; ++r){
      int i = ip + r;
      float4 ci0 = *(const float4*)(coords + i*NC);
      float4 ci1 = *(const float4*)(coords + i*NC + 4);
      float dd = 0.f;
      dd = fmaf(ci0.x-cj0.x, ci0.x-cj0.x, dd);
      dd = fmaf(ci0.y-cj0.y, ci0.y-cj0.y, dd);
      dd = fmaf(ci0.z-cj0.z, ci0.z-cj0.z, dd);
      dd = fmaf(ci0.w-cj0.w, ci0.w-cj0.w, dd);
      dd = fmaf(ci1.x-cj1.x, ci1.x-cj1.x, dd);
      dd = fmaf(ci1.y-cj1.y, ci1.y-cj1.y, dd);
      dd = fmaf(ci1.z-cj1.z, ci1.z-cj1.z, dd);
      dd = fmaf(ci1.w-cj1.w, ci1.w-cj1.w, dd);
      float dist = sqrtf(fmaxf(dd, 1e-12f));
      s_pri[r][j] = (j == i) ? be2v : fmaf(spps, 1.f/(1.f + dist), be2v);
    }
    s_invn[j] = invn[b*NN + j];
  }
  __syncthreads();   // s_hi ready

  // B-frags in LDS: wa copy + per-row cw = f16(Wj + diag(hi)*Wp)
  {
    int frag = tid >> 6;          // 0..7 = ks*4+nt
    int l2   = tid & 63;
    const u4* wsrc = (const u4*)wa16;
    *(u4*)&lds_wa[(frag*64 + l2)*4] = wsrc[frag*64 + l2];

    int ch0 = (frag >> 2)*32 + (l2 >> 4)*8;
    const float* wj = wjf + (frag*64 + l2)*8;
    const float* wp = wpf + (frag*64 + l2)*8;
    #pragma unroll
    for (int r = 0; r < 2; ++r){
      u4 u;
      #pragma unroll
      for (int d = 0; d < 4; ++d){
        float v0 = fmaf(s_hi[r][ch0 + 2*d],     wp[2*d],     wj[2*d]);
        float v1 = fmaf(s_hi[r][ch0 + 2*d + 1], wp[2*d + 1], wj[2*d + 1]);
        u[d] = pkh(v0, v1);
      }
      *(u4*)&lds_cw[r][(frag*64 + l2)*4] = u;
    }
  }

  // per-lane hi packed f16 for both rows
  const u4* hfv = (const u4*)hf16;
  u4 hiA[2][2];
  #pragma unroll
  for (int r = 0; r < 2; ++r){
    hiA[r][0] = hfv[(b*NN + ip + r)*8 + kg];
    hiA[r][1] = hfv[(b*NN + ip + r)*8 + kg + 4];
  }

  float pv4[2][4], we2q[4];
  #pragma unroll
  for (int nt = 0; nt < 4; ++nt){
    #pragma unroll
    for (int r = 0; r < 2; ++r)
      pv4[r][nt] = pvec[(b*NN + ip + r)*64 + nt*16 + q];
    we2q[nt] = We2[nt*16 + q];
  }
  float invni[2];
  invni[0] = invn[b*NN + ip];
  invni[1] = invn[b*NN + ip + 1];
  int srcl = (lane & 48) | (((lane >> 4) & 3) << 2) | (lane & 3);
  int r8 = lane >> 3, c8 = lane & 7;
  __syncthreads();   // lds_wa / lds_cw ready

  const u4 absm = (u4){0x7fff7fffu, 0x7fff7fffu, 0x7fff7fffu, 0x7fff7fffu};

  // prefetch tile s=0 into regs
  u4 g0, g1;
  {
    int jbase = w * 16;
    g0 = *(const u4*)((const unsigned*)hf16 + (size_t)(b*NN + jbase + r8)*32 + c8*4);
    g1 = *(const u4*)((const unsigned*)hf16 + (size_t)(b*NN + jbase + 8 + r8)*32 + c8*4);
  }

  #pragma unroll
  for (int s = 0; s < 4; ++s){
    int jbase = (w + s*8) * 16;
    unsigned* slice = &s_hj[w][s & 1][0];

    // write current tile's staged regs to this wave's LDS slice
    {
      unsigned* p0 = slice + r8*34 + c8*4;
      unsigned* p1 = slice + (8 + r8)*34 + c8*4;
      u2 t;
      t.x = g0.x; t.y = g0.y; *(u2*)p0 = t;
      t.x = g0.z; t.y = g0.w; *(u2*)(p0 + 2) = t;
      t.x = g1.x; t.y = g1.y; *(u2*)p1 = t;
      t.x = g1.z; t.y = g1.w; *(u2*)(p1 + 2) = t;
    }
    // issue next tile's global loads (overlap with this tile's compute)
    if (s < 3){
      int jn = (w + (s+1)*8) * 16;
      g0 = *(const u4*)((const unsigned*)hf16 + (size_t)(b*NN + jn + r8)*32 + c8*4);
      g1 = *(const u4*)((const unsigned*)hf16 + (size_t)(b*NN + jn + 8 + r8)*32 + c8*4);
    }

    // this lane's hj fragment (row q, k-slices kg)
    u4 hj0, hj1;
    {
      unsigned* rp = slice + q*34 + kg*4;
      u2 a0 = *(u2*)rp;
      u2 a1 = *(u2*)(rp + 2);
      u2 b0 = *(u2*)(rp + 16);
      u2 b1 = *(u2*)(rp + 18);
      hj0.x = a0.x; hj0.y = a0.y; hj0.z = a1.x; hj0.w = a1.y;
      hj1.x = b0.x; hj1.y = b0.y; hj1.z = b1.x; hj1.w = b1.y;
    }
    h8 hjv0 = __builtin_bit_cast(h8, hj0);
    h8 hjv1 = __builtin_bit_cast(h8, hj1);

    // inline per-lane f16 dot (for cos): 16 channels, both rows
    float dotp[2];
    #pragma unroll
    for (int r = 0; r < 2; ++r){
      float d0 = dot8(hiA[r][0], hj0, 0.f);
      dotp[r]  = dot8(hiA[r][1], hj1, d0);
    }

    f32x4 acc[2][4];
    #pragma unroll
    for (int r = 0; r < 2; ++r)
      #pragma unroll
      for (int nt = 0; nt < 4; ++nt)
        acc[r][nt] = (f32x4){pv4[r][nt], pv4[r][nt], pv4[r][nt], pv4[r][nt]};

    #pragma unroll
    for (int nt = 0; nt < 4; ++nt){
      h8 wA0 = __builtin_bit_cast(h8, *(const u4*)&lds_wa[((0*4 + nt)*64 + lane)*4]);
      h8 wA1 = __builtin_bit_cast(h8, *(const u4*)&lds_wa[((1*4 + nt)*64 + lane)*4]);
      #pragma unroll
      for (int r = 0; r < 2; ++r){
        h8 dh0 = __builtin_bit_cast(h8, hiA[r][0]) - hjv0;
        h8 dh1 = __builtin_bit_cast(h8, hiA[r][1]) - hjv1;
        h8 af0 = __builtin_bit_cast(h8, __builtin_bit_cast(u4, dh0) & absm);
        h8 af1 = __builtin_bit_cast(h8, __builtin_bit_cast(u4, dh1) & absm);
        h8 wC0 = __builtin_bit_cast(h8, *(const u4*)&lds_cw[r][((0*4 + nt)*64 + lane)*4]);
        h8 wC1 = __builtin_bit_cast(h8, *(const u4*)&lds_cw[r][((1*4 + nt)*64 + lane)*4]);
        acc[r][nt] = __builtin_amdgcn_mfma_f32_16x16x32_f16(af0, wA0, acc[r][nt], 0, 0, 0);
        acc[r][nt] = __builtin_amdgcn_mfma_f32_16x16x32_f16(af1, wA1, acc[r][nt], 0, 0, 0);
        acc[r][nt] = __builtin_amdgcn_mfma_f32_16x16x32_f16(hjv0, wC0, acc[r][nt], 0, 0, 0);
        acc[r][nt] = __builtin_amdgcn_mfma_f32_16x16x32_f16(hjv1, wC1, acc[r][nt], 0, 0, 0);
      }
    }

    // epilogue per row: relu + We2 dot, DPP reduce; add prior + cos
    #pragma unroll
    for (int r = 0; r < 2; ++r){
      float part[4] = {0.f, 0.f, 0.f, 0.f};
      #pragma unroll
      for (int nt = 0; nt < 4; ++nt)
        #pragma unroll
        for (int rr = 0; rr < 4; ++rr)
          part[rr] = fmaf(fmaxf(acc[r][nt][rr], 0.f), we2q[nt], part[rr]);
      #pragma unroll
      for (int rr = 0; rr < 4; ++rr) part[rr] = row16_sum(part[rr]);

      float dp = dotp[r];
      dp += __shfl_xor(dp, 16);
      dp += __shfl_xor(dp, 32);
      float dj = __shfl(dp, srcl);     // dot for j = jbase + kg*4 + (lane&3)

      if (q < 4){
        int j2 = jbase + kg*4 + q;
        float ps2 = part[0];
        ps2 = (q == 1) ? part[1] : ps2;
        ps2 = (q == 2) ? part[2] : ps2;
        ps2 = (q == 3) ? part[3] : ps2;
        float cosv = dj * invni[r] * s_invn[j2];
        lrow[r][j2] = ps2 + s_pri[r][j2] + spss * cosv;
      }
    }
  }
  __syncthreads();

  // fused dual-row softmax; diag override here
  float va = (tid == ip)     ? spsl : lrow[0][tid];
  float vb = (tid == ip + 1) ? spsl : lrow[1][tid];

  float ma = va, mb = vb;
  #pragma unroll
  for (int msk = 1; msk < 64; msk <<= 1){
    ma = fmaxf(ma, __shfl_xor(ma, msk));
    mb = fmaxf(mb, __shfl_xor(mb, msk));
  }
  if (lane == 0){ red[w] = ma; red[8 + w] = mb; }
  __syncthreads();
  ma = red[0]; mb = red[8];
  #pragma unroll
  for (int ww = 1; ww < 8; ++ww){
    ma = fmaxf(ma, red[ww]);
    mb = fmaxf(mb, red[8 + ww]);
  }

  float ea = expf((va - ma) * invt);
  float eb = expf((vb - mb) * invt);
  float sa = ea, sb = eb;
  #pragma unroll
  for (int msk = 1; msk < 64; msk <<= 1){
    sa += __shfl_xor(sa, msk);
    sb += __shfl_xor(sb, msk);
  }
  if (lane == 0){ red[16 + w] = sa; red[24 + w] = sb; }
  __syncthreads();
  sa = red[16]; sb = red[24];
  #pragma unroll
  for (int ww = 1; ww < 8; ++ww){
    sa += red[16 + ww];
    sb += red[24 + ww];
  }

  float oa = ea / sa;
  float ob = eb / sb;
  unsym[(size_t)(b*NN + ip)*NN + tid]     = oa;
  unsym[(size_t)(b*NN + ip + 1)*NN + tid] = ob;
  // transposed copy: unsymT[tid][ip], unsymT[tid][ip+1] (one float2 scatter)
  *(float2*)(unsymT + (size_t)(b*NN + tid)*NN + ip) = (float2){oa, ob};
}

// ---------------- Kernel D: symmetrize + renormalize (fully coalesced) -------
__global__ __launch_bounds__(512) void k_sym(
    const float* __restrict__ u, const float* __restrict__ ut,
    float* __restrict__ out){
  int blk = blockIdx.x;
  int b  = blk >> 8;
  int ip = (blk & 255) * 2;
  int tid  = threadIdx.x;
  int lane = tid & 63, w = tid >> 6;

  const float* ra  = u  + (size_t)(b*NN + ip) * NN;
  const float* rat = ut + (size_t)(b*NN + ip) * NN;
  const float* rb  = u  + (size_t)(b*NN + ip + 1) * NN;
  const float* rbt = ut + (size_t)(b*NN + ip + 1) * NN;
  float va = 0.5f*(ra[tid] + rat[tid]);
  float vb = 0.5f*(rb[tid] + rbt[tid]);

  float sa = va, sb = vb;
  #pragma unroll
  for (int msk = 1; msk < 64; msk <<= 1){
    sa += __shfl_xor(sa, msk);
    sb += __shfl_xor(sb, msk);
  }
  __shared__ float red[16];
  if (lane == 0){ red[w] = sa; red[8 + w] = sb; }
  __syncthreads();
  sa = red[0]; sb = red[8];
  #pragma unroll
  for (int ww = 1; ww < 8; ++ww){
    sa += red[ww];
    sb += red[8 + ww];
  }
  float ia = 1.f / fmaxf(sa, 1e-6f);
  float ib = 1.f / fmaxf(sb, 1e-6f);
  out[(size_t)(b*NN + ip)*NN + tid]     = va * ia;
  out[(size_t)(b*NN + ip + 1)*NN + tid] = vb * ib;
}

extern "C" void kernel_launch(void* const* d_in, const int* in_sizes, int n_in,
                              void* d_out, int out_size, void* d_ws, size_t ws_size,
                              hipStream_t stream){
  const float* x      = (const float*)d_in[0];
  const float* mask   = (const float*)d_in[1];
  const float* sctx   = (const float*)d_in[2];
  const float* coords = (const float*)d_in[3];
  const float* W1     = (const float*)d_in[4];
  const float* b1     = (const float*)d_in[5];
  const float* W2     = (const float*)d_in[6];
  const float* b2     = (const float*)d_in[7];
  const float* We1    = (const float*)d_in[8];
  const float* be1    = (const float*)d_in[9];
  const float* We2    = (const float*)d_in[10];
  const float* be2    = (const float*)d_in[11];
  const float* sl     = (const float*)d_in[12];
  const float* ps     = (const float*)d_in[13];
  const float* ss     = (const float*)d_in[14];
  const float* tp     = (const float*)d_in[15];

  float*    ws     = (float*)d_ws;
  float*    hgp    = ws + OFF_H;
  float*    pvecp  = ws + OFF_PVEC;
  unsigned* hf16p  = (unsigned*)(ws + OFF_HF16);
  float*    invnp  = ws + OFF_INVN;
  short*    wa16p  = (short*)(ws + OFF_WA16);
  float*    wjfp   = ws + OFF_WJF;
  float*    wpfp   = ws + OFF_WPF;
  float*    unsym  = ws + OFF_UNSYM;
  float*    unsymT = ws + OFF_UNSYMT;
  float*    out    = (float*)d_out;

  k_front <<<304, 256, 0, stream>>>(x, mask, sctx, W1, b1, W2, b2, We1, be1,
                                    hgp, pvecp, hf16p, invnp, wa16p, wjfp, wpfp);
  k_logits<<<NB*NN/2, 512, 0, stream>>>(hgp, pvecp, hf16p, invnp, wa16p, wjfp,
                                        wpfp, coords, We2, be2, sl, ps, ss, tp,
                                        unsym, unsymT);
  k_sym   <<<NB*NN/2, 512, 0, stream>>>(unsym, unsymT, out);
}